// Round 1
// baseline (6327.835 us; speedup 1.0000x reference)
//
#include <hip/hip_runtime.h>
#include <hip/hip_fp16.h>
#include <stdint.h>

#define B_ 64
#define T_ 2048
#define I_ 16
#define H_ 256
#define G_ 768   // 3*H

typedef _Float16 f16;
typedef _Float16 half2_t __attribute__((ext_vector_type(2)));

// ---------- fast math helpers ----------
__device__ __forceinline__ float fast_rcp(float x) {
#if __has_builtin(__builtin_amdgcn_rcpf)
    return __builtin_amdgcn_rcpf(x);
#else
    return 1.0f / x;
#endif
}
__device__ __forceinline__ float sigmoid_f(float x) {
    return fast_rcp(1.0f + __expf(-x));
}
__device__ __forceinline__ float tanh_f(float x) {
    float e = __expf(2.0f * x);
    return 1.0f - 2.0f * fast_rcp(e + 1.0f);
}

// packed-half2 dot: acc += a.h2 * b.h2 (fp32 accumulate)
__device__ __forceinline__ float fdot2(uint32_t a, uint32_t b, float c) {
#if __has_builtin(__builtin_amdgcn_fdot2)
    return __builtin_amdgcn_fdot2(__builtin_bit_cast(half2_t, a),
                                  __builtin_bit_cast(half2_t, b), c, false);
#else
    half2_t ha = __builtin_bit_cast(half2_t, a), hb = __builtin_bit_cast(half2_t, b);
    return c + (float)ha.x * (float)hb.x + (float)ha.y * (float)hb.y;
#endif
}
__device__ __forceinline__ float dot_u4(uint4 w, uint4 h, float acc) {
    acc = fdot2(w.x, h.x, acc);
    acc = fdot2(w.y, h.y, acc);
    acc = fdot2(w.z, h.z, acc);
    acc = fdot2(w.w, h.w, acc);
    return acc;
}

// ---------- weight fp32 -> packed fp16 conversion ----------
// layout (dwords): [0,98304) Whh0 | [98304,196608) Whh1 | [196608,294912) Wih1 | [294912,327680) W1
__global__ __launch_bounds__(256) void cvt_weights(const float* __restrict__ whh0,
                                                   const float* __restrict__ whh1,
                                                   const float* __restrict__ wih1,
                                                   const float* __restrict__ w1,
                                                   uint32_t* __restrict__ out) {
    int idx = blockIdx.x * 256 + threadIdx.x;
    if (idx >= 327680) return;
    const float* src; int local;
    if (idx < 98304)       { src = whh0; local = idx; }
    else if (idx < 196608) { src = whh1; local = idx - 98304; }
    else if (idx < 294912) { src = wih1; local = idx - 196608; }
    else                   { src = w1;   local = idx - 294912; }
    half2_t h;
    h.x = (f16)src[2 * local];
    h.y = (f16)src[2 * local + 1];
    out[idx] = __builtin_bit_cast(uint32_t, h);
}

// ---------- xg0 = bih0 + x @ Wih0^T  (K=16, fp32) ----------
// grid: C blocks (64 m-rows each), 256 threads
__global__ __launch_bounds__(256) void xg0_kernel(const float* __restrict__ x,
        const float* __restrict__ wih0, const float* __restrict__ bih0,
        float* __restrict__ xg, int t0, int C) {
    __shared__ __align__(16) float xs[64][16];
    int tid = threadIdx.x;
    int m0 = blockIdx.x * 64;
    {
        int r = tid >> 2, c4 = (tid & 3) * 4;
        int m = m0 + r;
        int b = m / C, tl = m - b * C;
        float4 v = *(const float4*)(x + (size_t)(b * T_ + t0 + tl) * I_ + c4);
        *(float4*)&xs[r][c4] = v;
    }
    __syncthreads();
    #pragma unroll
    for (int gi = 0; gi < 3; ++gi) {
        int g = gi * 256 + tid;
        const float4* wr = (const float4*)(wih0 + (size_t)g * I_);
        float4 w0 = wr[0], w1 = wr[1], w2 = wr[2], w3 = wr[3];
        float bias = bih0[g];
        float* outp = xg + (size_t)m0 * G_ + g;
        for (int m = 0; m < 64; ++m) {
            const float4* xr4 = (const float4*)xs[m];
            float4 a0 = xr4[0], a1 = xr4[1], a2 = xr4[2], a3 = xr4[3];
            float acc = bias;
            acc += a0.x*w0.x + a0.y*w0.y + a0.z*w0.z + a0.w*w0.w;
            acc += a1.x*w1.x + a1.y*w1.y + a1.z*w1.z + a1.w*w1.w;
            acc += a2.x*w2.x + a2.y*w2.y + a2.z*w2.z + a2.w*w2.w;
            acc += a3.x*w3.x + a3.y*w3.y + a3.z*w3.z + a3.w*w3.w;
            outp[(size_t)m * G_] = acc;
        }
    }
}

// ---------- xg1 = bih1 + h1 @ Wih1^T  (K=256, fp16 dot2) ----------
// grid: C blocks (64 m-rows each), 256 threads; h1 tile staged in LDS
__global__ __launch_bounds__(256) void xg1_kernel(const f16* __restrict__ h1,
        const uint32_t* __restrict__ wih1, const float* __restrict__ bih1,
        float* __restrict__ xg, int C) {
    __shared__ uint4 hs[2048]; // 64 rows x 32 uint4 (256 halves/row) = 32 KB
    int tid = threadIdx.x;
    int m0 = blockIdx.x * 64;
    const uint4* hsrc = (const uint4*)h1 + (size_t)m0 * 32;
    #pragma unroll
    for (int it = 0; it < 8; ++it) hs[tid + it * 256] = hsrc[tid + it * 256];
    __syncthreads();
    const uint4* wu = (const uint4*)wih1;
    #pragma unroll
    for (int gi = 0; gi < 3; ++gi) {
        int g = gi * 256 + tid;
        float bias = bih1[g];
        for (int mb = 0; mb < 4; ++mb) {
            float acc[16];
            #pragma unroll
            for (int m = 0; m < 16; ++m) acc[m] = 0.0f;
            for (int k8 = 0; k8 < 32; ++k8) {
                uint4 w4 = wu[(size_t)g * 32 + k8];
                #pragma unroll
                for (int m = 0; m < 16; ++m) {
                    uint4 h4 = hs[(mb * 16 + m) * 32 + k8];
                    acc[m] = dot_u4(w4, h4, acc[m]);
                }
            }
            #pragma unroll
            for (int m = 0; m < 16; ++m)
                xg[(size_t)(m0 + mb * 16 + m) * G_ + g] = acc[m] + bias;
        }
    }
}

// ---------- GRU recurrence: one WG per batch element, Whh fp16 resident in VGPRs ----------
// threads: tid = j*2 + hf ; j = hidden unit (owns gate rows j, j+256, j+512), hf = K-half
__global__ __launch_bounds__(512) void gru_rec(const uint32_t* __restrict__ whh, // [768*128] dwords
        const float* __restrict__ bhh,
        const float* __restrict__ xg,    // [64*C*768] fp32 (includes bih + x/h1 gates)
        f16* __restrict__ h_out,         // [64*C*256] fp16
        float* __restrict__ state,       // [64*256] fp32, persists across chunks
        int C) {
    __shared__ __align__(16) uint32_t hpk[2][128]; // double-buffered h as packed fp16
    int tid = threadIdx.x;
    int j = tid >> 1, hf = tid & 1;
    int b = blockIdx.x;

    // load resident weights: 3 rows x 128 halves (this thread's K-half) = 48 uint4 = 192 VGPRs
    uint4 w0[16], w1[16], w2[16];
    {
        const uint4* wu = (const uint4*)whh;
        int base0 = (j)       * 32 + hf * 16;
        int base1 = (j + 256) * 32 + hf * 16;
        int base2 = (j + 512) * 32 + hf * 16;
        #pragma unroll
        for (int u = 0; u < 16; ++u) {
            w0[u] = wu[base0 + u];
            w1[u] = wu[base1 + u];
            w2[u] = wu[base2 + u];
        }
    }
    float h_old = 0.0f, bhr = 0.0f, bhz = 0.0f, bhn = 0.0f;
    if (hf == 0) {
        h_old = state[b * 256 + j];
        bhr = bhh[j]; bhz = bhh[256 + j]; bhn = bhh[512 + j];
        ((f16*)hpk[0])[j] = (f16)h_old;
    }
    __syncthreads();

    const float* xgb = xg + (size_t)b * C * G_;
    f16* hob = h_out + (size_t)b * C * H_;

    for (int tl = 0; tl < C; ++tl) {
        int p = tl & 1;
        const float* xgt = xgb + (size_t)tl * G_;
        float xr = xgt[j], xz = xgt[256 + j], xn = xgt[512 + j];

        const uint4* hp4 = ((const uint4*)hpk[p]) + hf * 16;
        float accR = 0.0f, accZ = 0.0f, accN = 0.0f;
        #pragma unroll
        for (int s = 0; s < 4; ++s) {
            uint4 ha = hp4[s * 4 + 0];
            uint4 hb = hp4[s * 4 + 1];
            uint4 hc = hp4[s * 4 + 2];
            uint4 hd = hp4[s * 4 + 3];
            accR = dot_u4(w0[s * 4 + 0], ha, accR);
            accZ = dot_u4(w1[s * 4 + 0], ha, accZ);
            accN = dot_u4(w2[s * 4 + 0], ha, accN);
            accR = dot_u4(w0[s * 4 + 1], hb, accR);
            accZ = dot_u4(w1[s * 4 + 1], hb, accZ);
            accN = dot_u4(w2[s * 4 + 1], hb, accN);
            accR = dot_u4(w0[s * 4 + 2], hc, accR);
            accZ = dot_u4(w1[s * 4 + 2], hc, accZ);
            accN = dot_u4(w2[s * 4 + 2], hc, accN);
            accR = dot_u4(w0[s * 4 + 3], hd, accR);
            accZ = dot_u4(w1[s * 4 + 3], hd, accZ);
            accN = dot_u4(w2[s * 4 + 3], hd, accN);
        }
        // xg contributions: add exactly once per pair
        accR += (hf == 0) ? xr : 0.0f;
        accZ += (hf == 0) ? 0.0f : xz;
        // combine the two K-halves
        accR += __shfl_xor(accR, 1, 64);
        accZ += __shfl_xor(accZ, 1, 64);
        accN += __shfl_xor(accN, 1, 64);

        if (hf == 0) {
            float r = sigmoid_f(accR + bhr);
            float z = sigmoid_f(accZ + bhz);
            float n = tanh_f(xn + r * (accN + bhn));
            h_old = z * (h_old - n) + n;   // (1-z)*n + z*h
            f16 hh = (f16)h_old;
            hob[(size_t)tl * H_ + j] = hh;
            ((f16*)hpk[p ^ 1])[j] = hh;
        }
        __syncthreads();
    }
    if (hf == 0) state[b * 256 + j] = h_old;
}

// ---------- regressor: out = relu(b2 + W2 @ relu(b1 + W1 @ h2)) ----------
// grid: C blocks (64 m-rows each), 256 threads (one W1 row per thread)
__global__ __launch_bounds__(256) void regressor(const f16* __restrict__ h2,
        const uint32_t* __restrict__ w1, const float* __restrict__ b1,
        const float* __restrict__ w2, const float* __restrict__ b2,
        float* __restrict__ out, int t0, int C, int lgC) {
    __shared__ uint4 hs[2048];      // 64 x 32 uint4 = 32 KB
    __shared__ float red[4][64];
    int tid = threadIdx.x;
    int m0 = blockIdx.x * 64;
    const uint4* hsrc = (const uint4*)h2 + (size_t)m0 * 32;
    #pragma unroll
    for (int it = 0; it < 8; ++it) hs[tid + it * 256] = hsrc[tid + it * 256];
    __syncthreads();
    const uint4* wu = (const uint4*)w1;
    int g = tid;
    float bias1 = b1[g], w2g = w2[g];
    int wave = tid >> 6, lane = tid & 63;
    for (int mb = 0; mb < 4; ++mb) {
        float acc[16];
        #pragma unroll
        for (int m = 0; m < 16; ++m) acc[m] = 0.0f;
        for (int k8 = 0; k8 < 32; ++k8) {
            uint4 w4 = wu[(size_t)g * 32 + k8];
            #pragma unroll
            for (int m = 0; m < 16; ++m) {
                uint4 h4 = hs[(mb * 16 + m) * 32 + k8];
                acc[m] = dot_u4(w4, h4, acc[m]);
            }
        }
        #pragma unroll
        for (int m = 0; m < 16; ++m) {
            float pv = w2g * fmaxf(acc[m] + bias1, 0.0f);
            pv += __shfl_xor(pv, 1, 64);
            pv += __shfl_xor(pv, 2, 64);
            pv += __shfl_xor(pv, 4, 64);
            pv += __shfl_xor(pv, 8, 64);
            pv += __shfl_xor(pv, 16, 64);
            pv += __shfl_xor(pv, 32, 64);
            if (lane == 0) red[wave][mb * 16 + m] = pv;
        }
    }
    __syncthreads();
    if (tid < 64) {
        int m = m0 + tid;
        float v = red[0][tid] + red[1][tid] + red[2][tid] + red[3][tid] + b2[0];
        v = fmaxf(v, 0.0f);
        int b = m >> lgC, tl = m & (C - 1);
        out[(size_t)b * T_ + t0 + tl] = v;
    }
}

// ---------- host ----------
extern "C" void kernel_launch(void* const* d_in, const int* in_sizes, int n_in,
                              void* d_out, int out_size, void* d_ws, size_t ws_size,
                              hipStream_t stream) {
    const float* x    = (const float*)d_in[0];
    const float* Wih0 = (const float*)d_in[1];
    const float* Whh0 = (const float*)d_in[2];
    const float* bih0 = (const float*)d_in[3];
    const float* bhh0 = (const float*)d_in[4];
    const float* Wih1 = (const float*)d_in[5];
    const float* Whh1 = (const float*)d_in[6];
    const float* bih1 = (const float*)d_in[7];
    const float* bhh1 = (const float*)d_in[8];
    const float* W1   = (const float*)d_in[9];
    const float* b1   = (const float*)d_in[10];
    const float* W2   = (const float*)d_in[11];
    const float* b2   = (const float*)d_in[12];
    float* out = (float*)d_out;

    char* ws = (char*)d_ws;
    uint32_t* wcvt = (uint32_t*)ws;             // 327680 dwords = 1,310,720 B
    const uint32_t* whh0_16 = wcvt;
    const uint32_t* whh1_16 = wcvt + 98304;
    const uint32_t* wih1_16 = wcvt + 196608;
    const uint32_t* w1_16   = wcvt + 294912;
    float* state0 = (float*)(ws + 1310720);     // 64*256*4 = 65,536 B
    float* state1 = (float*)(ws + 1310720 + 65536);
    size_t fixed = 1310720 + 2 * 65536;         // 1,441,792 B

    // chunk size: h1(32768C) + h2(32768C) + xg(196608C) = 262,144*C bytes
    int C = 512;
    while (C > 8 && fixed + (size_t)C * 262144 > ws_size) C >>= 1;
    int lgC = 0; while ((1 << lgC) < C) lgC++;

    char* p = ws + fixed;
    f16* h1_buf = (f16*)p;   p += (size_t)64 * C * 256 * 2;
    f16* h2_buf = (f16*)p;   p += (size_t)64 * C * 256 * 2;
    float* xg_buf = (float*)p;

    cvt_weights<<<1280, 256, 0, stream>>>(Whh0, Whh1, Wih1, W1, wcvt);
    hipMemsetAsync(state0, 0, 2 * 65536, stream);

    for (int t0 = 0; t0 < T_; t0 += C) {
        xg0_kernel<<<C, 256, 0, stream>>>(x, Wih0, bih0, xg_buf, t0, C);
        gru_rec<<<64, 512, 0, stream>>>(whh0_16, bhh0, xg_buf, h1_buf, state0, C);
        xg1_kernel<<<C, 256, 0, stream>>>(h1_buf, wih1_16, bih1, xg_buf, C);
        gru_rec<<<64, 512, 0, stream>>>(whh1_16, bhh1, xg_buf, h2_buf, state1, C);
        regressor<<<C, 256, 0, stream>>>(h2_buf, w1_16, b1, W2, b2, out, t0, C, lgC);
    }
}

// Round 2
// 4543.903 us; speedup vs baseline: 1.3926x; 1.3926x over previous
//
#include <hip/hip_runtime.h>
#include <hip/hip_fp16.h>
#include <stdint.h>

#define B_ 64
#define T_ 2048
#define I_ 16
#define H_ 256
#define G_ 768   // 3*H

typedef _Float16 f16;
typedef _Float16 half2_t __attribute__((ext_vector_type(2)));

// ---------- fast math helpers ----------
__device__ __forceinline__ float fast_rcp(float x) {
#if __has_builtin(__builtin_amdgcn_rcpf)
    return __builtin_amdgcn_rcpf(x);
#else
    return 1.0f / x;
#endif
}
__device__ __forceinline__ float sigmoid_f(float x) {
    return fast_rcp(1.0f + __expf(-x));
}
__device__ __forceinline__ float tanh_f(float x) {
    float e = __expf(2.0f * x);
    return 1.0f - 2.0f * fast_rcp(e + 1.0f);
}

// packed-half2 dot: acc += a.h2 * b.h2 (fp32 accumulate)
__device__ __forceinline__ float fdot2(uint32_t a, uint32_t b, float c) {
#if __has_builtin(__builtin_amdgcn_fdot2)
    return __builtin_amdgcn_fdot2(__builtin_bit_cast(half2_t, a),
                                  __builtin_bit_cast(half2_t, b), c, false);
#else
    half2_t ha = __builtin_bit_cast(half2_t, a), hb = __builtin_bit_cast(half2_t, b);
    return c + (float)ha.x * (float)hb.x + (float)ha.y * (float)hb.y;
#endif
}
__device__ __forceinline__ float dot_u4(uint4 w, uint4 h, float acc) {
    acc = fdot2(w.x, h.x, acc);
    acc = fdot2(w.y, h.y, acc);
    acc = fdot2(w.z, h.z, acc);
    acc = fdot2(w.w, h.w, acc);
    return acc;
}

// ---------- weight fp32 -> packed fp16 conversion ----------
// layout (dwords): [0,98304) Whh0 | [98304,196608) Whh1 | [196608,294912) Wih1 | [294912,327680) W1
__global__ __launch_bounds__(256) void cvt_weights(const float* __restrict__ whh0,
                                                   const float* __restrict__ whh1,
                                                   const float* __restrict__ wih1,
                                                   const float* __restrict__ w1,
                                                   uint32_t* __restrict__ out) {
    int idx = blockIdx.x * 256 + threadIdx.x;
    if (idx >= 327680) return;
    const float* src; int local;
    if (idx < 98304)       { src = whh0; local = idx; }
    else if (idx < 196608) { src = whh1; local = idx - 98304; }
    else if (idx < 294912) { src = wih1; local = idx - 196608; }
    else                   { src = w1;   local = idx - 294912; }
    half2_t h;
    h.x = (f16)src[2 * local];
    h.y = (f16)src[2 * local + 1];
    out[idx] = __builtin_bit_cast(uint32_t, h);
}

// ---------- xg0 = bih0 + x @ Wih0^T  (K=16, fp32) ----------
__global__ __launch_bounds__(256) void xg0_kernel(const float* __restrict__ x,
        const float* __restrict__ wih0, const float* __restrict__ bih0,
        float* __restrict__ xg, int t0, int C) {
    __shared__ __align__(16) float xs[64][16];
    int tid = threadIdx.x;
    int m0 = blockIdx.x * 64;
    {
        int r = tid >> 2, c4 = (tid & 3) * 4;
        int m = m0 + r;
        int b = m / C, tl = m - b * C;
        float4 v = *(const float4*)(x + (size_t)(b * T_ + t0 + tl) * I_ + c4);
        *(float4*)&xs[r][c4] = v;
    }
    __syncthreads();
    #pragma unroll
    for (int gi = 0; gi < 3; ++gi) {
        int g = gi * 256 + tid;
        const float4* wr = (const float4*)(wih0 + (size_t)g * I_);
        float4 w0 = wr[0], w1 = wr[1], w2 = wr[2], w3 = wr[3];
        float bias = bih0[g];
        float* outp = xg + (size_t)m0 * G_ + g;
        for (int m = 0; m < 64; ++m) {
            const float4* xr4 = (const float4*)xs[m];
            float4 a0 = xr4[0], a1 = xr4[1], a2 = xr4[2], a3 = xr4[3];
            float acc = bias;
            acc += a0.x*w0.x + a0.y*w0.y + a0.z*w0.z + a0.w*w0.w;
            acc += a1.x*w1.x + a1.y*w1.y + a1.z*w1.z + a1.w*w1.w;
            acc += a2.x*w2.x + a2.y*w2.y + a2.z*w2.z + a2.w*w2.w;
            acc += a3.x*w3.x + a3.y*w3.y + a3.z*w3.z + a3.w*w3.w;
            outp[(size_t)m * G_] = acc;
        }
    }
}

// ---------- xg1 = bih1 + h1 @ Wih1^T  (K=256, fp16 dot2) ----------
__global__ __launch_bounds__(256) void xg1_kernel(const f16* __restrict__ h1,
        const uint32_t* __restrict__ wih1, const float* __restrict__ bih1,
        float* __restrict__ xg, int C) {
    __shared__ uint4 hs[2048]; // 64 rows x 32 uint4 = 32 KB
    int tid = threadIdx.x;
    int m0 = blockIdx.x * 64;
    const uint4* hsrc = (const uint4*)h1 + (size_t)m0 * 32;
    #pragma unroll
    for (int it = 0; it < 8; ++it) hs[tid + it * 256] = hsrc[tid + it * 256];
    __syncthreads();
    const uint4* wu = (const uint4*)wih1;
    #pragma unroll
    for (int gi = 0; gi < 3; ++gi) {
        int g = gi * 256 + tid;
        float bias = bih1[g];
        for (int mb = 0; mb < 4; ++mb) {
            float acc[16];
            #pragma unroll
            for (int m = 0; m < 16; ++m) acc[m] = 0.0f;
            for (int k8 = 0; k8 < 32; ++k8) {
                uint4 w4 = wu[(size_t)g * 32 + k8];
                #pragma unroll
                for (int m = 0; m < 16; ++m) {
                    uint4 h4 = hs[(mb * 16 + m) * 32 + k8];
                    acc[m] = dot_u4(w4, h4, acc[m]);
                }
            }
            #pragma unroll
            for (int m = 0; m < 16; ++m)
                xg[(size_t)(m0 + mb * 16 + m) * G_ + g] = acc[m] + bias;
        }
    }
}

// ---------- GRU recurrence, R=6/Q=4 layout ----------
// thread: g = tid>>2 (row-group 0..127), q = tid&3 (K-quarter).
// Owns rows {gate*256 + sub*128 + g : gate in 0..2, sub in 0..1}, K slice [q*64, q*64+64).
// h in LDS as 4 padded quarters (36 dwords each) -> per-instruction wave addresses hit
// disjoint bank groups (broadcast within 16-lane subsets, conflict-free).
// Combined dispatch: blocks 0..63 = stream A (layer0 chunk i), 64..127 = stream B (layer1 chunk i-1).
__global__ __launch_bounds__(512, 1) void gru_rec(
        const uint32_t* __restrict__ whhA, const float* __restrict__ bhhA,
        const float* __restrict__ xgA, f16* __restrict__ hA, float* __restrict__ stA,
        const uint32_t* __restrict__ whhB, const float* __restrict__ bhhB,
        const float* __restrict__ xgB, f16* __restrict__ hB, float* __restrict__ stB,
        int C, int runB) {
    int blk = blockIdx.x;
    const uint32_t* whh; const float* bhh; const float* xg; f16* hout; float* state; int b;
    if (blk < 64) { whh = whhA; bhh = bhhA; xg = xgA; hout = hA; state = stA; b = blk; }
    else {
        if (!runB) return;
        whh = whhB; bhh = bhhB; xg = xgB; hout = hB; state = stB; b = blk - 64;
    }

    __shared__ __align__(16) uint32_t hq[2][4][36]; // 2 buffers x 4 quarters x (32+4 pad) dwords

    int tid = threadIdx.x;
    int g = tid >> 2, q = tid & 3;

    // resident weights: 6 rows x 32 dwords (this K-quarter) = 48 uint4 = 192 VGPRs
    uint4 W[6][8];
    {
        const uint4* wu = (const uint4*)whh;
        #pragma unroll
        for (int t = 0; t < 6; ++t) {
            int gate = t >> 1, sub = t & 1;
            int base = (gate * 256 + sub * 128 + g) * 32 + q * 8;
            #pragma unroll
            for (int u = 0; u < 8; ++u) W[t][u] = wu[base + u];
        }
    }

    int j = g + (q << 7); // valid for q<2: hidden unit this lane finalizes
    float h_old = 0.0f, bhr = 0.0f, bhz = 0.0f, bhn = 0.0f;
    if (q < 2) {
        h_old = state[b * 256 + j];
        bhr = bhh[j]; bhz = bhh[256 + j]; bhn = bhh[512 + j];
        ((f16*)&hq[0][j >> 6][0])[j & 63] = (f16)h_old;
    }
    __syncthreads();

    const float* xgb = xg + (size_t)b * C * G_;
    f16* hob = hout + (size_t)b * C * H_;

    float xr = 0, xz = 0, xn = 0;
    if (q < 2) { xr = xgb[j]; xz = xgb[256 + j]; xn = xgb[512 + j]; }

    for (int tl = 0; tl < C; ++tl) {
        int p = tl & 1;
        // prefetch next step's input gates (hidden under the dot work)
        float nr = 0, nz = 0, nn = 0;
        if (q < 2 && tl + 1 < C) {
            const float* xgn = xgb + (size_t)(tl + 1) * G_;
            nr = xgn[j]; nz = xgn[256 + j]; nn = xgn[512 + j];
        }

        const uint4* hp = (const uint4*)&hq[p][q][0];
        float a0 = 0, a1 = 0, a2 = 0, a3 = 0, a4 = 0, a5 = 0;
        #pragma unroll
        for (int u = 0; u < 8; ++u) {
            uint4 hv = hp[u];
            a0 = dot_u4(W[0][u], hv, a0);
            a1 = dot_u4(W[1][u], hv, a1);
            a2 = dot_u4(W[2][u], hv, a2);
            a3 = dot_u4(W[3][u], hv, a3);
            a4 = dot_u4(W[4][u], hv, a4);
            a5 = dot_u4(W[5][u], hv, a5);
        }
        // reduce across the 4 K-quarter lanes (butterfly)
        a0 += __shfl_xor(a0, 1, 64); a0 += __shfl_xor(a0, 2, 64);
        a1 += __shfl_xor(a1, 1, 64); a1 += __shfl_xor(a1, 2, 64);
        a2 += __shfl_xor(a2, 1, 64); a2 += __shfl_xor(a2, 2, 64);
        a3 += __shfl_xor(a3, 1, 64); a3 += __shfl_xor(a3, 2, 64);
        a4 += __shfl_xor(a4, 1, 64); a4 += __shfl_xor(a4, 2, 64);
        a5 += __shfl_xor(a5, 1, 64); a5 += __shfl_xor(a5, 2, 64);

        if (q < 2) {
            float sumR = q ? a1 : a0;
            float sumZ = q ? a3 : a2;
            float sumN = q ? a5 : a4;
            float r = sigmoid_f(xr + sumR + bhr);
            float z = sigmoid_f(xz + sumZ + bhz);
            float n = tanh_f(xn + r * (sumN + bhn));
            h_old = z * (h_old - n) + n;   // (1-z)*n + z*h
            f16 hh = (f16)h_old;
            hob[(size_t)tl * H_ + j] = hh;
            ((f16*)&hq[p ^ 1][j >> 6][0])[j & 63] = hh;
        }
        __syncthreads();
        xr = nr; xz = nz; xn = nn;
    }
    if (q < 2) state[b * 256 + j] = h_old;
}

// ---------- regressor: out = relu(b2 + W2 @ relu(b1 + W1 @ h2)) ----------
__global__ __launch_bounds__(256) void regressor(const f16* __restrict__ h2,
        const uint32_t* __restrict__ w1, const float* __restrict__ b1,
        const float* __restrict__ w2, const float* __restrict__ b2,
        float* __restrict__ out, int t0, int C, int lgC) {
    __shared__ uint4 hs[2048];      // 64 x 32 uint4 = 32 KB
    __shared__ float red[4][64];
    int tid = threadIdx.x;
    int m0 = blockIdx.x * 64;
    const uint4* hsrc = (const uint4*)h2 + (size_t)m0 * 32;
    #pragma unroll
    for (int it = 0; it < 8; ++it) hs[tid + it * 256] = hsrc[tid + it * 256];
    __syncthreads();
    const uint4* wu = (const uint4*)w1;
    int g = tid;
    float bias1 = b1[g], w2g = w2[g];
    int wave = tid >> 6, lane = tid & 63;
    for (int mb = 0; mb < 4; ++mb) {
        float acc[16];
        #pragma unroll
        for (int m = 0; m < 16; ++m) acc[m] = 0.0f;
        for (int k8 = 0; k8 < 32; ++k8) {
            uint4 w4 = wu[(size_t)g * 32 + k8];
            #pragma unroll
            for (int m = 0; m < 16; ++m) {
                uint4 h4 = hs[(mb * 16 + m) * 32 + k8];
                acc[m] = dot_u4(w4, h4, acc[m]);
            }
        }
        #pragma unroll
        for (int m = 0; m < 16; ++m) {
            float pv = w2g * fmaxf(acc[m] + bias1, 0.0f);
            pv += __shfl_xor(pv, 1, 64);
            pv += __shfl_xor(pv, 2, 64);
            pv += __shfl_xor(pv, 4, 64);
            pv += __shfl_xor(pv, 8, 64);
            pv += __shfl_xor(pv, 16, 64);
            pv += __shfl_xor(pv, 32, 64);
            if (lane == 0) red[wave][mb * 16 + m] = pv;
        }
    }
    __syncthreads();
    if (tid < 64) {
        int m = m0 + tid;
        float v = red[0][tid] + red[1][tid] + red[2][tid] + red[3][tid] + b2[0];
        v = fmaxf(v, 0.0f);
        int b = m >> lgC, tl = m & (C - 1);
        out[(size_t)b * T_ + t0 + tl] = v;
    }
}

// ---------- host ----------
extern "C" void kernel_launch(void* const* d_in, const int* in_sizes, int n_in,
                              void* d_out, int out_size, void* d_ws, size_t ws_size,
                              hipStream_t stream) {
    const float* x    = (const float*)d_in[0];
    const float* Wih0 = (const float*)d_in[1];
    const float* Whh0 = (const float*)d_in[2];
    const float* bih0 = (const float*)d_in[3];
    const float* bhh0 = (const float*)d_in[4];
    const float* Wih1 = (const float*)d_in[5];
    const float* Whh1 = (const float*)d_in[6];
    const float* bih1 = (const float*)d_in[7];
    const float* bhh1 = (const float*)d_in[8];
    const float* W1   = (const float*)d_in[9];
    const float* b1   = (const float*)d_in[10];
    const float* W2   = (const float*)d_in[11];
    const float* b2   = (const float*)d_in[12];
    float* out = (float*)d_out;

    char* ws = (char*)d_ws;
    uint32_t* wcvt = (uint32_t*)ws;             // 327680 dwords = 1,310,720 B
    const uint32_t* whh0_16 = wcvt;
    const uint32_t* whh1_16 = wcvt + 98304;
    const uint32_t* wih1_16 = wcvt + 196608;
    const uint32_t* w1_16   = wcvt + 294912;
    float* state0 = (float*)(ws + 1310720);     // 64*256*4 = 65,536 B
    float* state1 = (float*)(ws + 1310720 + 65536);
    size_t fixed = 1310720 + 2 * 65536;         // 1,441,792 B

    // per-chunk buffers: xg0 (x2, 196608C each) + xg1 (196608C) + h1 + h2 (32768C each)
    int C = 512;
    while (C > 32 && fixed + (size_t)C * 655360 > ws_size) C >>= 1;
    int lgC = 0; while ((1 << lgC) < C) lgC++;
    int nC = T_ / C;

    char* p = ws + fixed;
    float* xg0_buf[2];
    xg0_buf[0] = (float*)p;  p += (size_t)C * 196608;
    xg0_buf[1] = (float*)p;  p += (size_t)C * 196608;
    float* xg1_buf = (float*)p; p += (size_t)C * 196608;
    f16* h1_buf = (f16*)p;   p += (size_t)C * 32768;
    f16* h2_buf = (f16*)p;

    cvt_weights<<<1280, 256, 0, stream>>>(Whh0, Whh1, Wih1, W1, wcvt);
    hipMemsetAsync(state0, 0, 2 * 65536, stream);
    xg0_kernel<<<C, 256, 0, stream>>>(x, Wih0, bih0, xg0_buf[0], 0, C);

    for (int i = 0; i < nC; ++i) {
        // layer0 chunk i  ||  layer1 chunk i-1
        gru_rec<<<128, 512, 0, stream>>>(
            whh0_16, bhh0, xg0_buf[i & 1], h1_buf, state0,
            whh1_16, bhh1, xg1_buf,        h2_buf, state1, C, i > 0);
        if (i + 1 < nC)
            xg0_kernel<<<C, 256, 0, stream>>>(x, Wih0, bih0, xg0_buf[(i + 1) & 1],
                                              (i + 1) * C, C);
        xg1_kernel<<<C, 256, 0, stream>>>(h1_buf, wih1_16, bih1, xg1_buf, C);
        if (i > 0)
            regressor<<<C, 256, 0, stream>>>(h2_buf, w1_16, b1, W2, b2, out,
                                             (i - 1) * C, C, lgC);
    }
    // tail: layer1 last chunk, then its regressor
    gru_rec<<<64, 512, 0, stream>>>(
        whh1_16, bhh1, xg1_buf, h2_buf, state1,
        whh1_16, bhh1, xg1_buf, h2_buf, state1, C, 0);
    regressor<<<C, 256, 0, stream>>>(h2_buf, w1_16, b1, W2, b2, out,
                                     (nC - 1) * C, C, lgC);
}

// Round 3
// 3647.361 us; speedup vs baseline: 1.7349x; 1.2458x over previous
//
#include <hip/hip_runtime.h>
#include <hip/hip_fp16.h>
#include <stdint.h>

#define B_ 64
#define T_ 2048
#define I_ 16
#define H_ 256
#define G_ 768   // 3*H

typedef _Float16 f16;
typedef _Float16 half2_t __attribute__((ext_vector_type(2)));

// ---------- fast math helpers ----------
__device__ __forceinline__ float fast_rcp(float x) {
#if __has_builtin(__builtin_amdgcn_rcpf)
    return __builtin_amdgcn_rcpf(x);
#else
    return 1.0f / x;
#endif
}
__device__ __forceinline__ float sigmoid_f(float x) {
    return fast_rcp(1.0f + __expf(-x));
}
__device__ __forceinline__ float tanh_f(float x) {
    float e = __expf(2.0f * x);
    return 1.0f - 2.0f * fast_rcp(e + 1.0f);
}

// packed-half2 dot: acc += a.h2 * b.h2 (fp32 accumulate)
__device__ __forceinline__ float fdot2(uint32_t a, uint32_t b, float c) {
#if __has_builtin(__builtin_amdgcn_fdot2)
    return __builtin_amdgcn_fdot2(__builtin_bit_cast(half2_t, a),
                                  __builtin_bit_cast(half2_t, b), c, false);
#else
    half2_t ha = __builtin_bit_cast(half2_t, a), hb = __builtin_bit_cast(half2_t, b);
    return c + (float)ha.x * (float)hb.x + (float)ha.y * (float)hb.y;
#endif
}
__device__ __forceinline__ float dot_u4(uint4 w, uint4 h, float acc) {
    acc = fdot2(w.x, h.x, acc);
    acc = fdot2(w.y, h.y, acc);
    acc = fdot2(w.z, h.z, acc);
    acc = fdot2(w.w, h.w, acc);
    return acc;
}

// ---------- weight fp32 -> packed fp16 conversion ----------
// dword layout: [0,98304) Whh0 row-major | [98304,196608) Whh1 row-major |
//               [196608,294912) Wih1T k-major | [294912,327680) W1T k-major
// row-major: dword = row*128 + kd, halves (2kd, 2kd+1) of row.
// k-major (T): uint4 u = k8*NG + g holds halves w[g][k8*8 .. k8*8+8).
__global__ __launch_bounds__(256) void cvt_weights(const float* __restrict__ whh0,
                                                   const float* __restrict__ whh1,
                                                   const float* __restrict__ wih1,
                                                   const float* __restrict__ w1,
                                                   uint32_t* __restrict__ out) {
    int idx = blockIdx.x * 256 + threadIdx.x;
    if (idx >= 327680) return;
    const float* s;
    if (idx < 196608) {
        const float* w = (idx < 98304) ? whh0 : whh1;
        int local = (idx < 98304) ? idx : idx - 98304;
        int row = local >> 7, kd = local & 127;
        s = w + (size_t)row * 256 + kd * 2;
    } else if (idx < 294912) {
        int local = idx - 196608;
        int u4 = local >> 2, d = local & 3;
        int k8 = u4 / 768, g = u4 - k8 * 768;
        s = wih1 + (size_t)g * 256 + k8 * 8 + d * 2;
    } else {
        int local = idx - 294912;
        int u4 = local >> 2, d = local & 3;
        int k8 = u4 >> 8, g = u4 & 255;
        s = w1 + (size_t)g * 256 + k8 * 8 + d * 2;
    }
    half2_t h;
    h.x = (f16)s[0];
    h.y = (f16)s[1];
    out[idx] = __builtin_bit_cast(uint32_t, h);
}

// ---------- xg0 = bih0 + x @ Wih0^T  (K=16, fp32) ----------
__global__ __launch_bounds__(256) void xg0_kernel(const float* __restrict__ x,
        const float* __restrict__ wih0, const float* __restrict__ bih0,
        float* __restrict__ xg, int t0, int C) {
    __shared__ __align__(16) float xs[64][16];
    int tid = threadIdx.x;
    int m0 = blockIdx.x * 64;
    {
        int r = tid >> 2, c4 = (tid & 3) * 4;
        int m = m0 + r;
        int b = m / C, tl = m - b * C;
        float4 v = *(const float4*)(x + (size_t)(b * T_ + t0 + tl) * I_ + c4);
        *(float4*)&xs[r][c4] = v;
    }
    __syncthreads();
    #pragma unroll
    for (int gi = 0; gi < 3; ++gi) {
        int g = gi * 256 + tid;
        const float4* wr = (const float4*)(wih0 + (size_t)g * I_);
        float4 w0 = wr[0], w1 = wr[1], w2 = wr[2], w3 = wr[3];
        float bias = bih0[g];
        float* outp = xg + (size_t)m0 * G_ + g;
        for (int m = 0; m < 64; ++m) {
            const float4* xr4 = (const float4*)xs[m];
            float4 a0 = xr4[0], a1 = xr4[1], a2 = xr4[2], a3 = xr4[3];
            float acc = bias;
            acc += a0.x*w0.x + a0.y*w0.y + a0.z*w0.z + a0.w*w0.w;
            acc += a1.x*w1.x + a1.y*w1.y + a1.z*w1.z + a1.w*w1.w;
            acc += a2.x*w2.x + a2.y*w2.y + a2.z*w2.z + a2.w*w2.w;
            acc += a3.x*w3.x + a3.y*w3.y + a3.z*w3.z + a3.w*w3.w;
            outp[(size_t)m * G_] = acc;
        }
    }
}

// ---------- xg1 = bih1 + h1 @ Wih1^T  (K=256, fp16 dot2, 8g x 8m register tile) ----------
// grid: dim3(C, 3); block 256 = 32 gg x 8 mg. Thread owns g = gbase+gg+32i (i<8),
// m = m0+mg*8+r (r<8). Each LDS h-read feeds 8 dot_u4 -> fdot2-issue-bound.
__global__ __launch_bounds__(256) void xg1_kernel(const f16* __restrict__ h1,
        const uint32_t* __restrict__ wih1T, const float* __restrict__ bih1,
        float* __restrict__ xg, int C) {
    __shared__ uint4 hs[64][32]; // 32 KB
    int tid = threadIdx.x;
    int m0 = blockIdx.x * 64;
    int gbase = blockIdx.y * 256;
    const uint4* hsrc = (const uint4*)h1 + (size_t)m0 * 32;
    #pragma unroll
    for (int it = 0; it < 8; ++it) {
        int o = tid + it * 256;
        hs[o >> 5][o & 31] = hsrc[o];
    }
    __syncthreads();
    int gg = tid & 31, mg = tid >> 5;
    const uint4* wt = (const uint4*)wih1T;
    float acc[8][8];
    #pragma unroll
    for (int i = 0; i < 8; ++i)
        #pragma unroll
        for (int r = 0; r < 8; ++r) acc[i][r] = 0.0f;
    for (int k8 = 0; k8 < 32; ++k8) {
        uint4 w[8], h[8];
        #pragma unroll
        for (int i = 0; i < 8; ++i) w[i] = wt[(size_t)k8 * 768 + gbase + gg + 32 * i];
        #pragma unroll
        for (int r = 0; r < 8; ++r) h[r] = hs[mg * 8 + r][k8];
        #pragma unroll
        for (int i = 0; i < 8; ++i)
            #pragma unroll
            for (int r = 0; r < 8; ++r)
                acc[i][r] = dot_u4(w[i], h[r], acc[i][r]);
    }
    #pragma unroll
    for (int i = 0; i < 8; ++i) {
        int g = gbase + gg + 32 * i;
        float bias = bih1[g];
        #pragma unroll
        for (int r = 0; r < 8; ++r)
            xg[(size_t)(m0 + mg * 8 + r) * G_ + g] = acc[i][r] + bias;
    }
}

// ---------- GRU recurrence, R=6/Q=4 layout (unchanged from R2) ----------
__global__ __launch_bounds__(512, 1) void gru_rec(
        const uint32_t* __restrict__ whhA, const float* __restrict__ bhhA,
        const float* __restrict__ xgA, f16* __restrict__ hA, float* __restrict__ stA,
        const uint32_t* __restrict__ whhB, const float* __restrict__ bhhB,
        const float* __restrict__ xgB, f16* __restrict__ hB, float* __restrict__ stB,
        int C, int runB) {
    int blk = blockIdx.x;
    const uint32_t* whh; const float* bhh; const float* xg; f16* hout; float* state; int b;
    if (blk < 64) { whh = whhA; bhh = bhhA; xg = xgA; hout = hA; state = stA; b = blk; }
    else {
        if (!runB) return;
        whh = whhB; bhh = bhhB; xg = xgB; hout = hB; state = stB; b = blk - 64;
    }

    __shared__ __align__(16) uint32_t hq[2][4][36];

    int tid = threadIdx.x;
    int g = tid >> 2, q = tid & 3;

    uint4 W[6][8];
    {
        const uint4* wu = (const uint4*)whh;
        #pragma unroll
        for (int t = 0; t < 6; ++t) {
            int gate = t >> 1, sub = t & 1;
            int base = (gate * 256 + sub * 128 + g) * 32 + q * 8;
            #pragma unroll
            for (int u = 0; u < 8; ++u) W[t][u] = wu[base + u];
        }
    }

    int j = g + (q << 7);
    float h_old = 0.0f, bhr = 0.0f, bhz = 0.0f, bhn = 0.0f;
    if (q < 2) {
        h_old = state[b * 256 + j];
        bhr = bhh[j]; bhz = bhh[256 + j]; bhn = bhh[512 + j];
        ((f16*)&hq[0][j >> 6][0])[j & 63] = (f16)h_old;
    }
    __syncthreads();

    const float* xgb = xg + (size_t)b * C * G_;
    f16* hob = hout + (size_t)b * C * H_;

    float xr = 0, xz = 0, xn = 0;
    if (q < 2) { xr = xgb[j]; xz = xgb[256 + j]; xn = xgb[512 + j]; }

    for (int tl = 0; tl < C; ++tl) {
        int p = tl & 1;
        float nr = 0, nz = 0, nn = 0;
        if (q < 2 && tl + 1 < C) {
            const float* xgn = xgb + (size_t)(tl + 1) * G_;
            nr = xgn[j]; nz = xgn[256 + j]; nn = xgn[512 + j];
        }

        const uint4* hp = (const uint4*)&hq[p][q][0];
        float a0 = 0, a1 = 0, a2 = 0, a3 = 0, a4 = 0, a5 = 0;
        #pragma unroll
        for (int u = 0; u < 8; ++u) {
            uint4 hv = hp[u];
            a0 = dot_u4(W[0][u], hv, a0);
            a1 = dot_u4(W[1][u], hv, a1);
            a2 = dot_u4(W[2][u], hv, a2);
            a3 = dot_u4(W[3][u], hv, a3);
            a4 = dot_u4(W[4][u], hv, a4);
            a5 = dot_u4(W[5][u], hv, a5);
        }
        a0 += __shfl_xor(a0, 1, 64); a0 += __shfl_xor(a0, 2, 64);
        a1 += __shfl_xor(a1, 1, 64); a1 += __shfl_xor(a1, 2, 64);
        a2 += __shfl_xor(a2, 1, 64); a2 += __shfl_xor(a2, 2, 64);
        a3 += __shfl_xor(a3, 1, 64); a3 += __shfl_xor(a3, 2, 64);
        a4 += __shfl_xor(a4, 1, 64); a4 += __shfl_xor(a4, 2, 64);
        a5 += __shfl_xor(a5, 1, 64); a5 += __shfl_xor(a5, 2, 64);

        if (q < 2) {
            float sumR = q ? a1 : a0;
            float sumZ = q ? a3 : a2;
            float sumN = q ? a5 : a4;
            float r = sigmoid_f(xr + sumR + bhr);
            float z = sigmoid_f(xz + sumZ + bhz);
            float n = tanh_f(xn + r * (sumN + bhn));
            h_old = z * (h_old - n) + n;
            f16 hh = (f16)h_old;
            hob[(size_t)tl * H_ + j] = hh;
            ((f16*)&hq[p ^ 1][j >> 6][0])[j & 63] = hh;
        }
        __syncthreads();
        xr = nr; xz = nz; xn = nn;
    }
    if (q < 2) state[b * 256 + j] = h_old;
}

// ---------- regressor: out = relu(b2 + W2 @ relu(b1 + W1 @ h2)), 8g x 8m tile ----------
__global__ __launch_bounds__(256) void regressor(const f16* __restrict__ h2,
        const uint32_t* __restrict__ w1T, const float* __restrict__ b1,
        const float* __restrict__ w2, const float* __restrict__ b2,
        float* __restrict__ out, int t0, int C, int lgC) {
    __shared__ uint4 hs[64][32];
    __shared__ float red[8][8];
    int tid = threadIdx.x;
    int m0 = blockIdx.x * 64;
    const uint4* hsrc = (const uint4*)h2 + (size_t)m0 * 32;
    #pragma unroll
    for (int it = 0; it < 8; ++it) {
        int o = tid + it * 256;
        hs[o >> 5][o & 31] = hsrc[o];
    }
    __syncthreads();
    int gg = tid & 31, mg = tid >> 5;
    const uint4* wt = (const uint4*)w1T;
    float acc[8][8];
    #pragma unroll
    for (int i = 0; i < 8; ++i)
        #pragma unroll
        for (int r = 0; r < 8; ++r) acc[i][r] = 0.0f;
    for (int k8 = 0; k8 < 32; ++k8) {
        uint4 w[8], h[8];
        #pragma unroll
        for (int i = 0; i < 8; ++i) w[i] = wt[(size_t)k8 * 256 + gg + 32 * i];
        #pragma unroll
        for (int r = 0; r < 8; ++r) h[r] = hs[mg * 8 + r][k8];
        #pragma unroll
        for (int i = 0; i < 8; ++i)
            #pragma unroll
            for (int r = 0; r < 8; ++r)
                acc[i][r] = dot_u4(w[i], h[r], acc[i][r]);
    }
    float pv[8];
    #pragma unroll
    for (int r = 0; r < 8; ++r) pv[r] = 0.0f;
    #pragma unroll
    for (int i = 0; i < 8; ++i) {
        int g = gg + 32 * i;
        float bias = b1[g], w2g = w2[g];
        #pragma unroll
        for (int r = 0; r < 8; ++r)
            pv[r] += w2g * fmaxf(acc[i][r] + bias, 0.0f);
    }
    #pragma unroll
    for (int r = 0; r < 8; ++r) {
        pv[r] += __shfl_xor(pv[r], 1, 64);
        pv[r] += __shfl_xor(pv[r], 2, 64);
        pv[r] += __shfl_xor(pv[r], 4, 64);
        pv[r] += __shfl_xor(pv[r], 8, 64);
        pv[r] += __shfl_xor(pv[r], 16, 64);
    }
    if (gg == 0) {
        #pragma unroll
        for (int r = 0; r < 8; ++r) red[mg][r] = pv[r];
    }
    __syncthreads();
    if (tid < 64) {
        int m = m0 + tid;
        float v = fmaxf(red[tid >> 3][tid & 7] + b2[0], 0.0f);
        int b = m >> lgC, tl = m & (C - 1);
        out[(size_t)b * T_ + t0 + tl] = v;
    }
}

// ---------- host ----------
extern "C" void kernel_launch(void* const* d_in, const int* in_sizes, int n_in,
                              void* d_out, int out_size, void* d_ws, size_t ws_size,
                              hipStream_t stream) {
    const float* x    = (const float*)d_in[0];
    const float* Wih0 = (const float*)d_in[1];
    const float* Whh0 = (const float*)d_in[2];
    const float* bih0 = (const float*)d_in[3];
    const float* bhh0 = (const float*)d_in[4];
    const float* Wih1 = (const float*)d_in[5];
    const float* Whh1 = (const float*)d_in[6];
    const float* bih1 = (const float*)d_in[7];
    const float* bhh1 = (const float*)d_in[8];
    const float* W1   = (const float*)d_in[9];
    const float* b1   = (const float*)d_in[10];
    const float* W2   = (const float*)d_in[11];
    const float* b2   = (const float*)d_in[12];
    float* out = (float*)d_out;

    char* ws = (char*)d_ws;
    uint32_t* wcvt = (uint32_t*)ws;             // 327680 dwords
    const uint32_t* whh0_16 = wcvt;
    const uint32_t* whh1_16 = wcvt + 98304;
    const uint32_t* wih1T   = wcvt + 196608;
    const uint32_t* w1T     = wcvt + 294912;
    float* state0 = (float*)(ws + 1310720);
    float* state1 = (float*)(ws + 1310720 + 65536);
    size_t fixed = 1310720 + 2 * 65536;

    // per-chunk buffers: xg0 (x2) + xg1 (196608C each) + h1 + h2 (32768C each)
    int C = 512;
    while (C > 32 && fixed + (size_t)C * 655360 > ws_size) C >>= 1;
    int lgC = 0; while ((1 << lgC) < C) lgC++;
    int nC = T_ / C;

    char* p = ws + fixed;
    float* xg0_buf[2];
    xg0_buf[0] = (float*)p;  p += (size_t)C * 196608;
    xg0_buf[1] = (float*)p;  p += (size_t)C * 196608;
    float* xg1_buf = (float*)p; p += (size_t)C * 196608;
    f16* h1_buf = (f16*)p;   p += (size_t)C * 32768;
    f16* h2_buf = (f16*)p;

    cvt_weights<<<1280, 256, 0, stream>>>(Whh0, Whh1, Wih1, W1, wcvt);
    hipMemsetAsync(state0, 0, 2 * 65536, stream);
    xg0_kernel<<<C, 256, 0, stream>>>(x, Wih0, bih0, xg0_buf[0], 0, C);

    for (int i = 0; i < nC; ++i) {
        // layer0 chunk i  ||  layer1 chunk i-1
        gru_rec<<<128, 512, 0, stream>>>(
            whh0_16, bhh0, xg0_buf[i & 1], h1_buf, state0,
            whh1_16, bhh1, xg1_buf,        h2_buf, state1, C, i > 0);
        if (i + 1 < nC)
            xg0_kernel<<<C, 256, 0, stream>>>(x, Wih0, bih0, xg0_buf[(i + 1) & 1],
                                              (i + 1) * C, C);
        xg1_kernel<<<dim3(C, 3), 256, 0, stream>>>(h1_buf, wih1T, bih1, xg1_buf, C);
        if (i > 0)
            regressor<<<C, 256, 0, stream>>>(h2_buf, w1T, b1, W2, b2, out,
                                             (i - 1) * C, C, lgC);
    }
    gru_rec<<<64, 512, 0, stream>>>(
        whh1_16, bhh1, xg1_buf, h2_buf, state1,
        whh1_16, bhh1, xg1_buf, h2_buf, state1, C, 0);
    regressor<<<C, 256, 0, stream>>>(h2_buf, w1T, b1, W2, b2, out,
                                     (nC - 1) * C, C, lgC);
}

// Round 4
// 3538.793 us; speedup vs baseline: 1.7881x; 1.0307x over previous
//
#include <hip/hip_runtime.h>
#include <hip/hip_fp16.h>
#include <stdint.h>

#define B_ 64
#define T_ 2048
#define I_ 16
#define H_ 256
#define G_ 768   // 3*H

typedef _Float16 f16;
typedef _Float16 half2_t __attribute__((ext_vector_type(2)));

// ---------- fast math helpers ----------
__device__ __forceinline__ float fast_rcp(float x) {
#if __has_builtin(__builtin_amdgcn_rcpf)
    return __builtin_amdgcn_rcpf(x);
#else
    return 1.0f / x;
#endif
}
__device__ __forceinline__ float sigmoid_f(float x) {
    return fast_rcp(1.0f + __expf(-x));
}
__device__ __forceinline__ float tanh_f(float x) {
    float e = __expf(2.0f * x);
    return 1.0f - 2.0f * fast_rcp(e + 1.0f);
}

// packed-half2 dot: acc += a.h2 * b.h2 (fp32 accumulate)
__device__ __forceinline__ float fdot2(uint32_t a, uint32_t b, float c) {
#if __has_builtin(__builtin_amdgcn_fdot2)
    return __builtin_amdgcn_fdot2(__builtin_bit_cast(half2_t, a),
                                  __builtin_bit_cast(half2_t, b), c, false);
#else
    half2_t ha = __builtin_bit_cast(half2_t, a), hb = __builtin_bit_cast(half2_t, b);
    return c + (float)ha.x * (float)hb.x + (float)ha.y * (float)hb.y;
#endif
}
__device__ __forceinline__ float dot_u4(uint4 w, uint4 h, float acc) {
    acc = fdot2(w.x, h.x, acc);
    acc = fdot2(w.y, h.y, acc);
    acc = fdot2(w.z, h.z, acc);
    acc = fdot2(w.w, h.w, acc);
    return acc;
}

// ---------- weight fp32 -> packed fp16 conversion ----------
// dword layout: [0,98304) Whh0 row-major | [98304,196608) Whh1 row-major |
//               [196608,294912) Wih1T k-major | [294912,327680) W1T k-major
__global__ __launch_bounds__(256) void cvt_weights(const float* __restrict__ whh0,
                                                   const float* __restrict__ whh1,
                                                   const float* __restrict__ wih1,
                                                   const float* __restrict__ w1,
                                                   uint32_t* __restrict__ out) {
    int idx = blockIdx.x * 256 + threadIdx.x;
    if (idx >= 327680) return;
    const float* s;
    if (idx < 196608) {
        const float* w = (idx < 98304) ? whh0 : whh1;
        int local = (idx < 98304) ? idx : idx - 98304;
        int row = local >> 7, kd = local & 127;
        s = w + (size_t)row * 256 + kd * 2;
    } else if (idx < 294912) {
        int local = idx - 196608;
        int u4 = local >> 2, d = local & 3;
        int k8 = u4 / 768, g = u4 - k8 * 768;
        s = wih1 + (size_t)g * 256 + k8 * 8 + d * 2;
    } else {
        int local = idx - 294912;
        int u4 = local >> 2, d = local & 3;
        int k8 = u4 >> 8, g = u4 & 255;
        s = w1 + (size_t)g * 256 + k8 * 8 + d * 2;
    }
    half2_t h;
    h.x = (f16)s[0];
    h.y = (f16)s[1];
    out[idx] = __builtin_bit_cast(uint32_t, h);
}

// ---------- xg0 = bih0 + x @ Wih0^T  (K=16, fp32) ----------
__global__ __launch_bounds__(256) void xg0_kernel(const float* __restrict__ x,
        const float* __restrict__ wih0, const float* __restrict__ bih0,
        float* __restrict__ xg, int t0, int C) {
    __shared__ __align__(16) float xs[64][16];
    int tid = threadIdx.x;
    int m0 = blockIdx.x * 64;
    {
        int r = tid >> 2, c4 = (tid & 3) * 4;
        int m = m0 + r;
        int b = m / C, tl = m - b * C;
        float4 v = *(const float4*)(x + (size_t)(b * T_ + t0 + tl) * I_ + c4);
        *(float4*)&xs[r][c4] = v;
    }
    __syncthreads();
    #pragma unroll
    for (int gi = 0; gi < 3; ++gi) {
        int g = gi * 256 + tid;
        const float4* wr = (const float4*)(wih0 + (size_t)g * I_);
        float4 w0 = wr[0], w1 = wr[1], w2 = wr[2], w3 = wr[3];
        float bias = bih0[g];
        float* outp = xg + (size_t)m0 * G_ + g;
        for (int m = 0; m < 64; ++m) {
            const float4* xr4 = (const float4*)xs[m];
            float4 a0 = xr4[0], a1 = xr4[1], a2 = xr4[2], a3 = xr4[3];
            float acc = bias;
            acc += a0.x*w0.x + a0.y*w0.y + a0.z*w0.z + a0.w*w0.w;
            acc += a1.x*w1.x + a1.y*w1.y + a1.z*w1.z + a1.w*w1.w;
            acc += a2.x*w2.x + a2.y*w2.y + a2.z*w2.z + a2.w*w2.w;
            acc += a3.x*w3.x + a3.y*w3.y + a3.z*w3.z + a3.w*w3.w;
            outp[(size_t)m * G_] = acc;
        }
    }
}

// ---------- xg1 = bih1 + h1 @ Wih1^T  (K=256, fp16 dot2, 8g x 8m register tile) ----------
__global__ __launch_bounds__(256) void xg1_kernel(const f16* __restrict__ h1,
        const uint32_t* __restrict__ wih1T, const float* __restrict__ bih1,
        float* __restrict__ xg, int C) {
    __shared__ uint4 hs[64][32]; // 32 KB
    int tid = threadIdx.x;
    int m0 = blockIdx.x * 64;
    int gbase = blockIdx.y * 256;
    const uint4* hsrc = (const uint4*)h1 + (size_t)m0 * 32;
    #pragma unroll
    for (int it = 0; it < 8; ++it) {
        int o = tid + it * 256;
        hs[o >> 5][o & 31] = hsrc[o];
    }
    __syncthreads();
    int gg = tid & 31, mg = tid >> 5;
    const uint4* wt = (const uint4*)wih1T;
    float acc[8][8];
    #pragma unroll
    for (int i = 0; i < 8; ++i)
        #pragma unroll
        for (int r = 0; r < 8; ++r) acc[i][r] = 0.0f;
    for (int k8 = 0; k8 < 32; ++k8) {
        uint4 w[8], h[8];
        #pragma unroll
        for (int i = 0; i < 8; ++i) w[i] = wt[(size_t)k8 * 768 + gbase + gg + 32 * i];
        #pragma unroll
        for (int r = 0; r < 8; ++r) h[r] = hs[mg * 8 + r][k8];
        #pragma unroll
        for (int i = 0; i < 8; ++i)
            #pragma unroll
            for (int r = 0; r < 8; ++r)
                acc[i][r] = dot_u4(w[i], h[r], acc[i][r]);
    }
    #pragma unroll
    for (int i = 0; i < 8; ++i) {
        int g = gbase + gg + 32 * i;
        float bias = bih1[g];
        #pragma unroll
        for (int r = 0; r < 8; ++r)
            xg[(size_t)(m0 + mg * 8 + r) * G_ + g] = acc[i][r] + bias;
    }
}

// ---------- GRU recurrence, R=6/Q=4, weights pinned in 48 named uint4 VGPRs ----------
// thread: g = tid>>2 (row-group), q = tid&3 (K-quarter).
// Rows {gate*256 + sub*128 + g}, K slice [q*64, q*64+64).
#define LOADROW(t, BASE) \
    uint4 W##t##0 = wu[(BASE) + 0], W##t##1 = wu[(BASE) + 1], \
          W##t##2 = wu[(BASE) + 2], W##t##3 = wu[(BASE) + 3], \
          W##t##4 = wu[(BASE) + 4], W##t##5 = wu[(BASE) + 5], \
          W##t##6 = wu[(BASE) + 6], W##t##7 = wu[(BASE) + 7];

#define DOTU(u) { uint4 hv = hp[u]; \
    a0 = dot_u4(W0##u, hv, a0); a1 = dot_u4(W1##u, hv, a1); \
    a2 = dot_u4(W2##u, hv, a2); a3 = dot_u4(W3##u, hv, a3); \
    a4 = dot_u4(W4##u, hv, a4); a5 = dot_u4(W5##u, hv, a5); }

__global__ __launch_bounds__(512, 2) void gru_rec(
        const uint32_t* __restrict__ whhA, const float* __restrict__ bhhA,
        const float* __restrict__ xgA, f16* __restrict__ hA, float* __restrict__ stA,
        const uint32_t* __restrict__ whhB, const float* __restrict__ bhhB,
        const float* __restrict__ xgB, f16* __restrict__ hB, float* __restrict__ stB,
        int C, int runB) {
    int blk = blockIdx.x;
    const uint32_t* whh; const float* bhh; const float* xg; f16* hout; float* state; int b;
    if (blk < 64) { whh = whhA; bhh = bhhA; xg = xgA; hout = hA; state = stA; b = blk; }
    else {
        if (!runB) return;
        whh = whhB; bhh = bhhB; xg = xgB; hout = hB; state = stB; b = blk - 64;
    }

    __shared__ __align__(16) uint32_t hq[2][4][36]; // padded quarters: conflict-free broadcast

    int tid = threadIdx.x;
    int g = tid >> 2, q = tid & 3;

    const uint4* wu = (const uint4*)whh;
    // 6 rows x 8 uint4 = 48 named uint4 = 192 VGPRs, pinned below.
    LOADROW(0, (g)             * 32 + q * 8)   // gate r, sub 0  (j = g)
    LOADROW(1, (128 + g)       * 32 + q * 8)   // gate r, sub 1  (j = g+128)
    LOADROW(2, (256 + g)       * 32 + q * 8)   // gate z, sub 0
    LOADROW(3, (384 + g)       * 32 + q * 8)   // gate z, sub 1
    LOADROW(4, (512 + g)       * 32 + q * 8)   // gate n, sub 0
    LOADROW(5, (640 + g)       * 32 + q * 8)   // gate n, sub 1

    int j = g + (q << 7); // valid for q<2
    float h_old = 0.0f, bhr = 0.0f, bhz = 0.0f, bhn = 0.0f;
    if (q < 2) {
        h_old = state[b * 256 + j];
        bhr = bhh[j]; bhz = bhh[256 + j]; bhn = bhh[512 + j];
        ((f16*)&hq[0][j >> 6][0])[j & 63] = (f16)h_old;
    }
    // Loads above may NOT be sunk/rematerialized past this point:
    asm volatile("" ::: "memory");
    __syncthreads();

    const float* xgt = xg + (size_t)b * C * G_;
    f16* hob = hout + (size_t)b * C * H_;

    for (int tl = 0; tl < C; ++tl) {
        int p = tl & 1;
        // issue this step's input-gate loads early; consumed after the dots
        float xr = 0, xz = 0, xn = 0;
        if (q < 2) { xr = xgt[j]; xz = xgt[256 + j]; xn = xgt[512 + j]; }

        const uint4* hp = (const uint4*)&hq[p][q][0];
        float a0 = 0, a1 = 0, a2 = 0, a3 = 0, a4 = 0, a5 = 0;
        DOTU(0) DOTU(1) DOTU(2) DOTU(3) DOTU(4) DOTU(5) DOTU(6) DOTU(7)

        // reduce across the 4 K-quarter lanes (butterfly)
        a0 += __shfl_xor(a0, 1, 64); a0 += __shfl_xor(a0, 2, 64);
        a1 += __shfl_xor(a1, 1, 64); a1 += __shfl_xor(a1, 2, 64);
        a2 += __shfl_xor(a2, 1, 64); a2 += __shfl_xor(a2, 2, 64);
        a3 += __shfl_xor(a3, 1, 64); a3 += __shfl_xor(a3, 2, 64);
        a4 += __shfl_xor(a4, 1, 64); a4 += __shfl_xor(a4, 2, 64);
        a5 += __shfl_xor(a5, 1, 64); a5 += __shfl_xor(a5, 2, 64);

        if (q < 2) {
            float sumR = q ? a1 : a0;
            float sumZ = q ? a3 : a2;
            float sumN = q ? a5 : a4;
            float r = sigmoid_f(xr + sumR + bhr);
            float z = sigmoid_f(xz + sumZ + bhz);
            float n = tanh_f(xn + r * (sumN + bhn));
            h_old = z * (h_old - n) + n;   // (1-z)*n + z*h
            f16 hh = (f16)h_old;
            hob[(size_t)tl * H_ + j] = hh;
            ((f16*)&hq[p ^ 1][j >> 6][0])[j & 63] = hh;
        }
        __syncthreads();
        xgt += G_;
    }
    if (q < 2) state[b * 256 + j] = h_old;
}

// ---------- regressor: out = relu(b2 + W2 @ relu(b1 + W1 @ h2)), 8g x 8m tile ----------
__global__ __launch_bounds__(256) void regressor(const f16* __restrict__ h2,
        const uint32_t* __restrict__ w1T, const float* __restrict__ b1,
        const float* __restrict__ w2, const float* __restrict__ b2,
        float* __restrict__ out, int t0, int C, int lgC) {
    __shared__ uint4 hs[64][32];
    __shared__ float red[8][8];
    int tid = threadIdx.x;
    int m0 = blockIdx.x * 64;
    const uint4* hsrc = (const uint4*)h2 + (size_t)m0 * 32;
    #pragma unroll
    for (int it = 0; it < 8; ++it) {
        int o = tid + it * 256;
        hs[o >> 5][o & 31] = hsrc[o];
    }
    __syncthreads();
    int gg = tid & 31, mg = tid >> 5;
    const uint4* wt = (const uint4*)w1T;
    float acc[8][8];
    #pragma unroll
    for (int i = 0; i < 8; ++i)
        #pragma unroll
        for (int r = 0; r < 8; ++r) acc[i][r] = 0.0f;
    for (int k8 = 0; k8 < 32; ++k8) {
        uint4 w[8], h[8];
        #pragma unroll
        for (int i = 0; i < 8; ++i) w[i] = wt[(size_t)k8 * 256 + gg + 32 * i];
        #pragma unroll
        for (int r = 0; r < 8; ++r) h[r] = hs[mg * 8 + r][k8];
        #pragma unroll
        for (int i = 0; i < 8; ++i)
            #pragma unroll
            for (int r = 0; r < 8; ++r)
                acc[i][r] = dot_u4(w[i], h[r], acc[i][r]);
    }
    float pv[8];
    #pragma unroll
    for (int r = 0; r < 8; ++r) pv[r] = 0.0f;
    #pragma unroll
    for (int i = 0; i < 8; ++i) {
        int g = gg + 32 * i;
        float bias = b1[g], w2g = w2[g];
        #pragma unroll
        for (int r = 0; r < 8; ++r)
            pv[r] += w2g * fmaxf(acc[i][r] + bias, 0.0f);
    }
    #pragma unroll
    for (int r = 0; r < 8; ++r) {
        pv[r] += __shfl_xor(pv[r], 1, 64);
        pv[r] += __shfl_xor(pv[r], 2, 64);
        pv[r] += __shfl_xor(pv[r], 4, 64);
        pv[r] += __shfl_xor(pv[r], 8, 64);
        pv[r] += __shfl_xor(pv[r], 16, 64);
    }
    if (gg == 0) {
        #pragma unroll
        for (int r = 0; r < 8; ++r) red[mg][r] = pv[r];
    }
    __syncthreads();
    if (tid < 64) {
        int m = m0 + tid;
        float v = fmaxf(red[tid >> 3][tid & 7] + b2[0], 0.0f);
        int b = m >> lgC, tl = m & (C - 1);
        out[(size_t)b * T_ + t0 + tl] = v;
    }
}

// ---------- host ----------
extern "C" void kernel_launch(void* const* d_in, const int* in_sizes, int n_in,
                              void* d_out, int out_size, void* d_ws, size_t ws_size,
                              hipStream_t stream) {
    const float* x    = (const float*)d_in[0];
    const float* Wih0 = (const float*)d_in[1];
    const float* Whh0 = (const float*)d_in[2];
    const float* bih0 = (const float*)d_in[3];
    const float* bhh0 = (const float*)d_in[4];
    const float* Wih1 = (const float*)d_in[5];
    const float* Whh1 = (const float*)d_in[6];
    const float* bih1 = (const float*)d_in[7];
    const float* bhh1 = (const float*)d_in[8];
    const float* W1   = (const float*)d_in[9];
    const float* b1   = (const float*)d_in[10];
    const float* W2   = (const float*)d_in[11];
    const float* b2   = (const float*)d_in[12];
    float* out = (float*)d_out;

    char* ws = (char*)d_ws;
    uint32_t* wcvt = (uint32_t*)ws;             // 327680 dwords
    const uint32_t* whh0_16 = wcvt;
    const uint32_t* whh1_16 = wcvt + 98304;
    const uint32_t* wih1T   = wcvt + 196608;
    const uint32_t* w1T     = wcvt + 294912;
    float* state0 = (float*)(ws + 1310720);
    float* state1 = (float*)(ws + 1310720 + 65536);
    size_t fixed = 1310720 + 2 * 65536;

    // per-chunk buffers: xg0 (x2) + xg1 (196608C each) + h1 + h2 (32768C each)
    int C = 512;
    while (C > 32 && fixed + (size_t)C * 655360 > ws_size) C >>= 1;
    int lgC = 0; while ((1 << lgC) < C) lgC++;
    int nC = T_ / C;

    char* p = ws + fixed;
    float* xg0_buf[2];
    xg0_buf[0] = (float*)p;  p += (size_t)C * 196608;
    xg0_buf[1] = (float*)p;  p += (size_t)C * 196608;
    float* xg1_buf = (float*)p; p += (size_t)C * 196608;
    f16* h1_buf = (f16*)p;   p += (size_t)C * 32768;
    f16* h2_buf = (f16*)p;

    cvt_weights<<<1280, 256, 0, stream>>>(Whh0, Whh1, Wih1, W1, wcvt);
    hipMemsetAsync(state0, 0, 2 * 65536, stream);
    xg0_kernel<<<C, 256, 0, stream>>>(x, Wih0, bih0, xg0_buf[0], 0, C);

    for (int i = 0; i < nC; ++i) {
        // layer0 chunk i  ||  layer1 chunk i-1
        gru_rec<<<128, 512, 0, stream>>>(
            whh0_16, bhh0, xg0_buf[i & 1], h1_buf, state0,
            whh1_16, bhh1, xg1_buf,        h2_buf, state1, C, i > 0);
        if (i + 1 < nC)
            xg0_kernel<<<C, 256, 0, stream>>>(x, Wih0, bih0, xg0_buf[(i + 1) & 1],
                                              (i + 1) * C, C);
        xg1_kernel<<<dim3(C, 3), 256, 0, stream>>>(h1_buf, wih1T, bih1, xg1_buf, C);
        if (i > 0)
            regressor<<<C, 256, 0, stream>>>(h2_buf, w1T, b1, W2, b2, out,
                                             (i - 1) * C, C, lgC);
    }
    gru_rec<<<64, 512, 0, stream>>>(
        whh1_16, bhh1, xg1_buf, h2_buf, state1,
        whh1_16, bhh1, xg1_buf, h2_buf, state1, C, 0);
    regressor<<<C, 256, 0, stream>>>(h2_buf, w1T, b1, W2, b2, out,
                                     (nC - 1) * C, C, lgC);
}

// Round 5
// 3325.120 us; speedup vs baseline: 1.9030x; 1.0643x over previous
//
#include <hip/hip_runtime.h>
#include <hip/hip_fp16.h>
#include <stdint.h>

#define B_ 64
#define T_ 2048
#define I_ 16
#define H_ 256
#define G_ 768   // 3*H

typedef _Float16 f16;
typedef _Float16 half2_t __attribute__((ext_vector_type(2)));
typedef uint32_t u32x4 __attribute__((ext_vector_type(4)));

// ---------- fast math helpers ----------
__device__ __forceinline__ float fast_rcp(float x) {
#if __has_builtin(__builtin_amdgcn_rcpf)
    return __builtin_amdgcn_rcpf(x);
#else
    return 1.0f / x;
#endif
}
__device__ __forceinline__ float sigmoid_f(float x) {
    return fast_rcp(1.0f + __expf(-x));
}
__device__ __forceinline__ float tanh_f(float x) {
    float e = __expf(2.0f * x);
    return 1.0f - 2.0f * fast_rcp(e + 1.0f);
}

__device__ __forceinline__ float fdot2(uint32_t a, uint32_t b, float c) {
#if __has_builtin(__builtin_amdgcn_fdot2)
    return __builtin_amdgcn_fdot2(__builtin_bit_cast(half2_t, a),
                                  __builtin_bit_cast(half2_t, b), c, false);
#else
    half2_t ha = __builtin_bit_cast(half2_t, a), hb = __builtin_bit_cast(half2_t, b);
    return c + (float)ha.x * (float)hb.x + (float)ha.y * (float)hb.y;
#endif
}
__device__ __forceinline__ float dot_u4(u32x4 w, u32x4 h, float acc) {
    acc = fdot2(w.x, h.x, acc);
    acc = fdot2(w.y, h.y, acc);
    acc = fdot2(w.z, h.z, acc);
    acc = fdot2(w.w, h.w, acc);
    return acc;
}

// ---------- weight fp32 -> packed fp16 conversion ----------
// dword layout: [0,98304) Whh0 row-major | [98304,196608) Whh1 row-major |
//               [196608,294912) Wih1T k-major | [294912,327680) W1T k-major
__global__ __launch_bounds__(256) void cvt_weights(const float* __restrict__ whh0,
                                                   const float* __restrict__ whh1,
                                                   const float* __restrict__ wih1,
                                                   const float* __restrict__ w1,
                                                   uint32_t* __restrict__ out) {
    int idx = blockIdx.x * 256 + threadIdx.x;
    if (idx >= 327680) return;
    const float* s;
    if (idx < 196608) {
        const float* w = (idx < 98304) ? whh0 : whh1;
        int local = (idx < 98304) ? idx : idx - 98304;
        int row = local >> 7, kd = local & 127;
        s = w + (size_t)row * 256 + kd * 2;
    } else if (idx < 294912) {
        int local = idx - 196608;
        int u4 = local >> 2, d = local & 3;
        int k8 = u4 / 768, g = u4 - k8 * 768;
        s = wih1 + (size_t)g * 256 + k8 * 8 + d * 2;
    } else {
        int local = idx - 294912;
        int u4 = local >> 2, d = local & 3;
        int k8 = u4 >> 8, g = u4 & 255;
        s = w1 + (size_t)g * 256 + k8 * 8 + d * 2;
    }
    half2_t h;
    h.x = (f16)s[0];
    h.y = (f16)s[1];
    out[idx] = __builtin_bit_cast(uint32_t, h);
}

// =======================================================================
// role bodies (shared between fused dispatch and standalone wrappers)
// =======================================================================

// ---------- xg0: 512 threads, one 64-row tile ----------
__device__ __forceinline__ void xg0_body(const float* __restrict__ x,
        const float* __restrict__ wih0, const float* __restrict__ bih0,
        float* __restrict__ xg, int t0, int C, int blk, char* smem) {
    float (*xs)[16] = (float(*)[16])smem;
    int tid = threadIdx.x;
    int m0 = blk * 64;
    if (tid < 256) {
        int r = tid >> 2, c4 = (tid & 3) * 4;
        int m = m0 + r;
        int b = m / C, tl = m - b * C;
        float4 v = *(const float4*)(x + (size_t)(b * T_ + t0 + tl) * I_ + c4);
        *(float4*)&xs[r][c4] = v;
    }
    __syncthreads();
    for (int g = tid; g < G_; g += 512) {
        const float4* wr = (const float4*)(wih0 + (size_t)g * I_);
        float4 w0 = wr[0], w1 = wr[1], w2 = wr[2], w3 = wr[3];
        float bias = bih0[g];
        float* outp = xg + (size_t)m0 * G_ + g;
        for (int m = 0; m < 64; ++m) {
            const float4* xr4 = (const float4*)xs[m];
            float4 a0 = xr4[0], a1 = xr4[1], a2 = xr4[2], a3 = xr4[3];
            float acc = bias;
            acc += a0.x*w0.x + a0.y*w0.y + a0.z*w0.z + a0.w*w0.w;
            acc += a1.x*w1.x + a1.y*w1.y + a1.z*w1.z + a1.w*w1.w;
            acc += a2.x*w2.x + a2.y*w2.y + a2.z*w2.z + a2.w*w2.w;
            acc += a3.x*w3.x + a3.y*w3.y + a3.z*w3.z + a3.w*w3.w;
            outp[(size_t)m * G_] = acc;
        }
    }
}

// ---------- regressor: 512 threads, one 64-row tile, 8g x 4m register tile ----------
__device__ __forceinline__ void reg_body(const f16* __restrict__ h2,
        const uint32_t* __restrict__ w1T, const float* __restrict__ b1,
        const float* __restrict__ w2, const float* __restrict__ b2,
        float* __restrict__ out, int t0, int C, int lgC, int blk, char* smem) {
    u32x4 (*hs)[32] = (u32x4(*)[32])smem;            // 32 KB
    float (*red)[4] = (float(*)[4])(smem + 32768);   // [16][4]
    int tid = threadIdx.x;
    int m0 = blk * 64;
    const u32x4* hsrc = (const u32x4*)h2 + (size_t)m0 * 32;
    #pragma unroll
    for (int it = 0; it < 4; ++it) {
        int o = tid + it * 512;
        hs[o >> 5][o & 31] = hsrc[o];
    }
    __syncthreads();
    int gg = tid & 31, mg = tid >> 5;
    const u32x4* wt = (const u32x4*)w1T;
    float acc[8][4];
    #pragma unroll
    for (int i = 0; i < 8; ++i)
        #pragma unroll
        for (int r = 0; r < 4; ++r) acc[i][r] = 0.0f;
    for (int k8 = 0; k8 < 32; ++k8) {
        u32x4 w[8], h[4];
        #pragma unroll
        for (int i = 0; i < 8; ++i) w[i] = wt[(size_t)k8 * 256 + gg + 32 * i];
        #pragma unroll
        for (int r = 0; r < 4; ++r) h[r] = hs[mg * 4 + r][k8];
        #pragma unroll
        for (int i = 0; i < 8; ++i)
            #pragma unroll
            for (int r = 0; r < 4; ++r)
                acc[i][r] = dot_u4(w[i], h[r], acc[i][r]);
    }
    float pv[4] = {0, 0, 0, 0};
    #pragma unroll
    for (int i = 0; i < 8; ++i) {
        int g = gg + 32 * i;
        float bias = b1[g], w2g = w2[g];
        #pragma unroll
        for (int r = 0; r < 4; ++r)
            pv[r] += w2g * fmaxf(acc[i][r] + bias, 0.0f);
    }
    #pragma unroll
    for (int r = 0; r < 4; ++r) {
        pv[r] += __shfl_xor(pv[r], 1, 64);
        pv[r] += __shfl_xor(pv[r], 2, 64);
        pv[r] += __shfl_xor(pv[r], 4, 64);
        pv[r] += __shfl_xor(pv[r], 8, 64);
        pv[r] += __shfl_xor(pv[r], 16, 64);
    }
    if (gg == 0) {
        #pragma unroll
        for (int r = 0; r < 4; ++r) red[mg][r] = pv[r];
    }
    __syncthreads();
    if (tid < 64) {
        int m = m0 + tid;
        float v = fmaxf(red[tid >> 2][tid & 3] + b2[0], 0.0f);
        int b = m >> lgC, tl = m & (C - 1);
        out[(size_t)b * T_ + t0 + tl] = v;
    }
}

// ---------- GRU recurrence, R=6/Q=4, weights pinned via "+v" asm each iteration ----------
#define LOADROW(t, BASE) \
    u32x4 W##t##0 = wu[(BASE) + 0], W##t##1 = wu[(BASE) + 1], \
          W##t##2 = wu[(BASE) + 2], W##t##3 = wu[(BASE) + 3], \
          W##t##4 = wu[(BASE) + 4], W##t##5 = wu[(BASE) + 5], \
          W##t##6 = wu[(BASE) + 6], W##t##7 = wu[(BASE) + 7];

// read-write pin: the asm "defines" the registers, so RA cannot substitute a reload
#define PINROW(t) asm volatile("" : \
    "+v"(W##t##0), "+v"(W##t##1), "+v"(W##t##2), "+v"(W##t##3), \
    "+v"(W##t##4), "+v"(W##t##5), "+v"(W##t##6), "+v"(W##t##7))

#define DOTU(u) { u32x4 hv = hp[u]; \
    a0 = dot_u4(W0##u, hv, a0); a1 = dot_u4(W1##u, hv, a1); \
    a2 = dot_u4(W2##u, hv, a2); a3 = dot_u4(W3##u, hv, a3); \
    a4 = dot_u4(W4##u, hv, a4); a5 = dot_u4(W5##u, hv, a5); }

__device__ __forceinline__ void rec_body(const uint32_t* __restrict__ whh,
        const float* __restrict__ bhh, const float* __restrict__ xg,
        f16* __restrict__ hout, float* __restrict__ state,
        int b, int C, char* smem) {
    uint32_t (*hq)[4][36] = (uint32_t(*)[4][36])smem; // padded quarters, conflict-free

    int tid = threadIdx.x;
    int g = tid >> 2, q = tid & 3;

    const u32x4* wu = (const u32x4*)whh;
    LOADROW(0, (g)       * 32 + q * 8)
    LOADROW(1, (128 + g) * 32 + q * 8)
    LOADROW(2, (256 + g) * 32 + q * 8)
    LOADROW(3, (384 + g) * 32 + q * 8)
    LOADROW(4, (512 + g) * 32 + q * 8)
    LOADROW(5, (640 + g) * 32 + q * 8)

    int j = g + (q << 7); // valid for q<2
    float h_old = 0.0f, bhr = 0.0f, bhz = 0.0f, bhn = 0.0f;
    if (q < 2) {
        h_old = state[b * 256 + j];
        bhr = bhh[j]; bhz = bhh[256 + j]; bhn = bhh[512 + j];
        ((f16*)&hq[0][j >> 6][0])[j & 63] = (f16)h_old;
    }
    __syncthreads();

    const float* xgt = xg + (size_t)b * C * G_;
    f16* hob = hout + (size_t)b * C * H_;

    for (int tl = 0; tl < C; ++tl) {
        // pin all 48 weight vectors: live-through the back-edge, reload impossible
        PINROW(0); PINROW(1); PINROW(2); PINROW(3); PINROW(4); PINROW(5);

        int p = tl & 1;
        float xr = 0, xz = 0, xn = 0;
        if (q < 2) { xr = xgt[j]; xz = xgt[256 + j]; xn = xgt[512 + j]; }

        const u32x4* hp = (const u32x4*)&hq[p][q][0];
        float a0 = 0, a1 = 0, a2 = 0, a3 = 0, a4 = 0, a5 = 0;
        DOTU(0) DOTU(1) DOTU(2) DOTU(3) DOTU(4) DOTU(5) DOTU(6) DOTU(7)

        a0 += __shfl_xor(a0, 1, 64); a0 += __shfl_xor(a0, 2, 64);
        a1 += __shfl_xor(a1, 1, 64); a1 += __shfl_xor(a1, 2, 64);
        a2 += __shfl_xor(a2, 1, 64); a2 += __shfl_xor(a2, 2, 64);
        a3 += __shfl_xor(a3, 1, 64); a3 += __shfl_xor(a3, 2, 64);
        a4 += __shfl_xor(a4, 1, 64); a4 += __shfl_xor(a4, 2, 64);
        a5 += __shfl_xor(a5, 1, 64); a5 += __shfl_xor(a5, 2, 64);

        if (q < 2) {
            float sumR = q ? a1 : a0;
            float sumZ = q ? a3 : a2;
            float sumN = q ? a5 : a4;
            float r = sigmoid_f(xr + sumR + bhr);
            float z = sigmoid_f(xz + sumZ + bhz);
            float n = tanh_f(xn + r * (sumN + bhn));
            h_old = z * (h_old - n) + n;   // (1-z)*n + z*h
            f16 hh = (f16)h_old;
            hob[(size_t)tl * H_ + j] = hh;
            ((f16*)&hq[p ^ 1][j >> 6][0])[j & 63] = hh;
        }
        __syncthreads();
        xgt += G_;
    }
    if (q < 2) state[b * 256 + j] = h_old;
}

// =======================================================================
// fused dispatch: blocks [0,64) rec0(i) | [64,128) rec1(i-1) |
//                 [128,128+C) xg0(i+1) | [128+C,128+2C) regressor(i-2)
// =======================================================================
__global__ __launch_bounds__(512, 2) void fused_step(int i, int nC, int C, int lgC,
        const float* __restrict__ x,
        const float* __restrict__ wih0, const float* __restrict__ bih0,
        const uint32_t* __restrict__ whh0, const float* __restrict__ bhh0,
        const uint32_t* __restrict__ whh1, const float* __restrict__ bhh1,
        const uint32_t* __restrict__ w1T, const float* __restrict__ b1,
        const float* __restrict__ w2, const float* __restrict__ b2,
        float* __restrict__ xg0a, float* __restrict__ xg0b,
        float* __restrict__ xg1b,
        f16* __restrict__ h1,
        f16* __restrict__ h2a, f16* __restrict__ h2b,
        float* __restrict__ st0, float* __restrict__ st1,
        float* __restrict__ out) {
    __shared__ __align__(16) char smem[33024];
    int blk = blockIdx.x;
    if (blk < 128) {
        const uint32_t* whh; const float* bhh; const float* xgp; f16* hout; float* st; int b;
        if (blk < 64) {
            if (i >= nC) return;
            whh = whh0; bhh = bhh0; xgp = (i & 1) ? xg0b : xg0a;
            hout = h1; st = st0; b = blk;
        } else {
            if (i < 1) return;
            whh = whh1; bhh = bhh1; xgp = xg1b;
            hout = ((i - 1) & 1) ? h2b : h2a; st = st1; b = blk - 64;
        }
        rec_body(whh, bhh, xgp, hout, st, b, C, smem);
    } else if (blk < 128 + C) {
        if (i + 1 >= nC) return;
        xg0_body(x, wih0, bih0, ((i + 1) & 1) ? xg0b : xg0a, (i + 1) * C, C, blk - 128, smem);
    } else {
        if (i < 2) return;
        reg_body((i & 1) ? h2b : h2a, w1T, b1, w2, b2, out, (i - 2) * C, C, lgC,
                 blk - 128 - C, smem);
    }
}

// ---------- standalone wrappers ----------
__global__ __launch_bounds__(512, 2) void xg0_stand(const float* __restrict__ x,
        const float* __restrict__ wih0, const float* __restrict__ bih0,
        float* __restrict__ xg, int t0, int C) {
    __shared__ __align__(16) char smem[4096];
    xg0_body(x, wih0, bih0, xg, t0, C, blockIdx.x, smem);
}

__global__ __launch_bounds__(512, 2) void reg_stand(const f16* __restrict__ h2,
        const uint32_t* __restrict__ w1T, const float* __restrict__ b1,
        const float* __restrict__ w2, const float* __restrict__ b2,
        float* __restrict__ out, int t0, int C, int lgC) {
    __shared__ __align__(16) char smem[33024];
    reg_body(h2, w1T, b1, w2, b2, out, t0, C, lgC, blockIdx.x, smem);
}

// ---------- xg1 = bih1 + h1 @ Wih1^T  (standalone, on critical path) ----------
__global__ __launch_bounds__(256) void xg1_kernel(const f16* __restrict__ h1,
        const uint32_t* __restrict__ wih1T, const float* __restrict__ bih1,
        float* __restrict__ xg, int C) {
    __shared__ u32x4 hs[64][32]; // 32 KB
    int tid = threadIdx.x;
    int m0 = blockIdx.x * 64;
    int gbase = blockIdx.y * 256;
    const u32x4* hsrc = (const u32x4*)h1 + (size_t)m0 * 32;
    #pragma unroll
    for (int it = 0; it < 8; ++it) {
        int o = tid + it * 256;
        hs[o >> 5][o & 31] = hsrc[o];
    }
    __syncthreads();
    int gg = tid & 31, mg = tid >> 5;
    const u32x4* wt = (const u32x4*)wih1T;
    float acc[8][8];
    #pragma unroll
    for (int i = 0; i < 8; ++i)
        #pragma unroll
        for (int r = 0; r < 8; ++r) acc[i][r] = 0.0f;
    for (int k8 = 0; k8 < 32; ++k8) {
        u32x4 w[8], h[8];
        #pragma unroll
        for (int i = 0; i < 8; ++i) w[i] = wt[(size_t)k8 * 768 + gbase + gg + 32 * i];
        #pragma unroll
        for (int r = 0; r < 8; ++r) h[r] = hs[mg * 8 + r][k8];
        #pragma unroll
        for (int i = 0; i < 8; ++i)
            #pragma unroll
            for (int r = 0; r < 8; ++r)
                acc[i][r] = dot_u4(w[i], h[r], acc[i][r]);
    }
    #pragma unroll
    for (int i = 0; i < 8; ++i) {
        int g = gbase + gg + 32 * i;
        float bias = bih1[g];
        #pragma unroll
        for (int r = 0; r < 8; ++r)
            xg[(size_t)(m0 + mg * 8 + r) * G_ + g] = acc[i][r] + bias;
    }
}

// ---------- host ----------
extern "C" void kernel_launch(void* const* d_in, const int* in_sizes, int n_in,
                              void* d_out, int out_size, void* d_ws, size_t ws_size,
                              hipStream_t stream) {
    const float* x    = (const float*)d_in[0];
    const float* Wih0 = (const float*)d_in[1];
    const float* Whh0 = (const float*)d_in[2];
    const float* bih0 = (const float*)d_in[3];
    const float* bhh0 = (const float*)d_in[4];
    const float* Wih1 = (const float*)d_in[5];
    const float* Whh1 = (const float*)d_in[6];
    const float* bih1 = (const float*)d_in[7];
    const float* bhh1 = (const float*)d_in[8];
    const float* W1   = (const float*)d_in[9];
    const float* b1   = (const float*)d_in[10];
    const float* W2   = (const float*)d_in[11];
    const float* b2   = (const float*)d_in[12];
    float* out = (float*)d_out;

    char* ws = (char*)d_ws;
    uint32_t* wcvt = (uint32_t*)ws;             // 327680 dwords
    const uint32_t* whh0_16 = wcvt;
    const uint32_t* whh1_16 = wcvt + 98304;
    const uint32_t* wih1T   = wcvt + 196608;
    const uint32_t* w1T     = wcvt + 294912;
    float* state0 = (float*)(ws + 1310720);
    float* state1 = (float*)(ws + 1310720 + 65536);
    size_t fixed = 1310720 + 2 * 65536;

    // per-chunk: xg0 x2 + xg1 (196608C each) + h1 (32768C) + h2 x2 (32768C each)
    int C = 512;
    while (C > 32 && fixed + (size_t)C * 688128 > ws_size) C >>= 1;
    int lgC = 0; while ((1 << lgC) < C) lgC++;
    int nC = T_ / C;

    char* p = ws + fixed;
    float* xg0_buf[2];
    xg0_buf[0] = (float*)p;  p += (size_t)C * 196608;
    xg0_buf[1] = (float*)p;  p += (size_t)C * 196608;
    float* xg1_buf = (float*)p; p += (size_t)C * 196608;
    f16* h1_buf = (f16*)p;   p += (size_t)C * 32768;
    f16* h2_buf[2];
    h2_buf[0] = (f16*)p;     p += (size_t)C * 32768;
    h2_buf[1] = (f16*)p;

    cvt_weights<<<1280, 256, 0, stream>>>(Whh0, Whh1, Wih1, W1, wcvt);
    hipMemsetAsync(state0, 0, 2 * 65536, stream);
    xg0_stand<<<C, 512, 0, stream>>>(x, Wih0, bih0, xg0_buf[0], 0, C);

    for (int i = 0; i <= nC; ++i) {
        fused_step<<<128 + 2 * C, 512, 0, stream>>>(i, nC, C, lgC,
            x, Wih0, bih0, whh0_16, bhh0, whh1_16, bhh1, w1T, b1, W2, b2,
            xg0_buf[0], xg0_buf[1], xg1_buf, h1_buf, h2_buf[0], h2_buf[1],
            state0, state1, out);
        if (i < nC)
            xg1_kernel<<<dim3(C, 3), 256, 0, stream>>>(h1_buf, wih1T, bih1, xg1_buf, C);
    }
    reg_stand<<<C, 512, 0, stream>>>(h2_buf[(nC - 1) & 1], w1T, b1, W2, b2, out,
                                     (nC - 1) * C, C, lgC);
}

// Round 6
// 3274.997 us; speedup vs baseline: 1.9322x; 1.0153x over previous
//
#include <hip/hip_runtime.h>
#include <hip/hip_fp16.h>
#include <stdint.h>

#define B_ 64
#define T_ 2048
#define I_ 16
#define H_ 256
#define G_ 768   // 3*H

typedef _Float16 f16;
typedef _Float16 half2_t __attribute__((ext_vector_type(2)));
typedef uint32_t u32x4 __attribute__((ext_vector_type(4)));

// ---------- fast math helpers ----------
__device__ __forceinline__ float fast_rcp(float x) {
#if __has_builtin(__builtin_amdgcn_rcpf)
    return __builtin_amdgcn_rcpf(x);
#else
    return 1.0f / x;
#endif
}
__device__ __forceinline__ float sigmoid_f(float x) {
    return fast_rcp(1.0f + __expf(-x));
}
__device__ __forceinline__ float tanh_f(float x) {
    float e = __expf(2.0f * x);
    return 1.0f - 2.0f * fast_rcp(e + 1.0f);
}

__device__ __forceinline__ float fdot2(uint32_t a, uint32_t b, float c) {
#if __has_builtin(__builtin_amdgcn_fdot2)
    return __builtin_amdgcn_fdot2(__builtin_bit_cast(half2_t, a),
                                  __builtin_bit_cast(half2_t, b), c, false);
#else
    half2_t ha = __builtin_bit_cast(half2_t, a), hb = __builtin_bit_cast(half2_t, b);
    return c + (float)ha.x * (float)hb.x + (float)ha.y * (float)hb.y;
#endif
}
__device__ __forceinline__ float dot_u4(u32x4 w, u32x4 h, float acc) {
    acc = fdot2(w.x, h.x, acc);
    acc = fdot2(w.y, h.y, acc);
    acc = fdot2(w.z, h.z, acc);
    acc = fdot2(w.w, h.w, acc);
    return acc;
}

// asm-def weight load: the def is an INLINEASM — RA can neither rematerialize it
// nor re-load it (it does not know the value came from memory). This is the pin.
__device__ __forceinline__ u32x4 wload(const u32x4* p) {
    u32x4 r;
    asm volatile("global_load_dwordx4 %0, %1, off" : "=v"(r) : "v"(p));
    return r;
}

// ---------- weight fp32 -> packed fp16 conversion ----------
// dword layout: [0,98304) Whh0 row-major | [98304,196608) Whh1 row-major |
//               [196608,294912) Wih1T k-major | [294912,327680) W1T k-major
__global__ __launch_bounds__(256) void cvt_weights(const float* __restrict__ whh0,
                                                   const float* __restrict__ whh1,
                                                   const float* __restrict__ wih1,
                                                   const float* __restrict__ w1,
                                                   uint32_t* __restrict__ out) {
    int idx = blockIdx.x * 256 + threadIdx.x;
    if (idx >= 327680) return;
    const float* s;
    if (idx < 196608) {
        const float* w = (idx < 98304) ? whh0 : whh1;
        int local = (idx < 98304) ? idx : idx - 98304;
        int row = local >> 7, kd = local & 127;
        s = w + (size_t)row * 256 + kd * 2;
    } else if (idx < 294912) {
        int local = idx - 196608;
        int u4 = local >> 2, d = local & 3;
        int k8 = u4 / 768, g = u4 - k8 * 768;
        s = wih1 + (size_t)g * 256 + k8 * 8 + d * 2;
    } else {
        int local = idx - 294912;
        int u4 = local >> 2, d = local & 3;
        int k8 = u4 >> 8, g = u4 & 255;
        s = w1 + (size_t)g * 256 + k8 * 8 + d * 2;
    }
    half2_t h;
    h.x = (f16)s[0];
    h.y = (f16)s[1];
    out[idx] = __builtin_bit_cast(uint32_t, h);
}

// =======================================================================
// role bodies
// =======================================================================

// ---------- xg0: 512 threads, one 64-row tile ----------
__device__ __forceinline__ void xg0_body(const float* __restrict__ x,
        const float* __restrict__ wih0, const float* __restrict__ bih0,
        float* __restrict__ xg, int t0, int C, int blk, char* smem) {
    float (*xs)[16] = (float(*)[16])smem;
    int tid = threadIdx.x;
    int m0 = blk * 64;
    if (tid < 256) {
        int r = tid >> 2, c4 = (tid & 3) * 4;
        int m = m0 + r;
        int b = m / C, tl = m - b * C;
        float4 v = *(const float4*)(x + (size_t)(b * T_ + t0 + tl) * I_ + c4);
        *(float4*)&xs[r][c4] = v;
    }
    __syncthreads();
    for (int g = tid; g < G_; g += 512) {
        const float4* wr = (const float4*)(wih0 + (size_t)g * I_);
        float4 w0 = wr[0], w1 = wr[1], w2 = wr[2], w3 = wr[3];
        float bias = bih0[g];
        float* outp = xg + (size_t)m0 * G_ + g;
        for (int m = 0; m < 64; ++m) {
            const float4* xr4 = (const float4*)xs[m];
            float4 a0 = xr4[0], a1 = xr4[1], a2 = xr4[2], a3 = xr4[3];
            float acc = bias;
            acc += a0.x*w0.x + a0.y*w0.y + a0.z*w0.z + a0.w*w0.w;
            acc += a1.x*w1.x + a1.y*w1.y + a1.z*w1.z + a1.w*w1.w;
            acc += a2.x*w2.x + a2.y*w2.y + a2.z*w2.z + a2.w*w2.w;
            acc += a3.x*w3.x + a3.y*w3.y + a3.z*w3.z + a3.w*w3.w;
            outp[(size_t)m * G_] = acc;
        }
    }
}

// ---------- regressor: 512 threads, one 64-row tile, 8g x 4m register tile ----------
__device__ __forceinline__ void reg_body(const f16* __restrict__ h2,
        const uint32_t* __restrict__ w1T, const float* __restrict__ b1,
        const float* __restrict__ w2, const float* __restrict__ b2,
        float* __restrict__ out, int t0, int C, int lgC, int blk, char* smem) {
    u32x4 (*hs)[32] = (u32x4(*)[32])smem;            // 32 KB
    float (*red)[4] = (float(*)[4])(smem + 32768);   // [16][4]
    int tid = threadIdx.x;
    int m0 = blk * 64;
    const u32x4* hsrc = (const u32x4*)h2 + (size_t)m0 * 32;
    #pragma unroll
    for (int it = 0; it < 4; ++it) {
        int o = tid + it * 512;
        hs[o >> 5][o & 31] = hsrc[o];
    }
    __syncthreads();
    int gg = tid & 31, mg = tid >> 5;
    const u32x4* wt = (const u32x4*)w1T;
    float acc[8][4];
    #pragma unroll
    for (int i = 0; i < 8; ++i)
        #pragma unroll
        for (int r = 0; r < 4; ++r) acc[i][r] = 0.0f;
    for (int k8 = 0; k8 < 32; ++k8) {
        u32x4 w[8], h[4];
        #pragma unroll
        for (int i = 0; i < 8; ++i) w[i] = wt[(size_t)k8 * 256 + gg + 32 * i];
        #pragma unroll
        for (int r = 0; r < 4; ++r) h[r] = hs[mg * 4 + r][k8];
        #pragma unroll
        for (int i = 0; i < 8; ++i)
            #pragma unroll
            for (int r = 0; r < 4; ++r)
                acc[i][r] = dot_u4(w[i], h[r], acc[i][r]);
    }
    float pv[4] = {0, 0, 0, 0};
    #pragma unroll
    for (int i = 0; i < 8; ++i) {
        int g = gg + 32 * i;
        float bias = b1[g], w2g = w2[g];
        #pragma unroll
        for (int r = 0; r < 4; ++r)
            pv[r] += w2g * fmaxf(acc[i][r] + bias, 0.0f);
    }
    #pragma unroll
    for (int r = 0; r < 4; ++r) {
        pv[r] += __shfl_xor(pv[r], 1, 64);
        pv[r] += __shfl_xor(pv[r], 2, 64);
        pv[r] += __shfl_xor(pv[r], 4, 64);
        pv[r] += __shfl_xor(pv[r], 8, 64);
        pv[r] += __shfl_xor(pv[r], 16, 64);
    }
    if (gg == 0) {
        #pragma unroll
        for (int r = 0; r < 4; ++r) red[mg][r] = pv[r];
    }
    __syncthreads();
    if (tid < 64) {
        int m = m0 + tid;
        float v = fmaxf(red[tid >> 2][tid & 3] + b2[0], 0.0f);
        int b = m >> lgC, tl = m & (C - 1);
        out[(size_t)b * T_ + t0 + tl] = v;
    }
}

// ---------- GRU recurrence, R=6/Q=4, weights resident via asm-def loads ----------
#define LOADROW(t, BASE) \
    u32x4 W##t##0 = wload(wu + (BASE) + 0), W##t##1 = wload(wu + (BASE) + 1), \
          W##t##2 = wload(wu + (BASE) + 2), W##t##3 = wload(wu + (BASE) + 3), \
          W##t##4 = wload(wu + (BASE) + 4), W##t##5 = wload(wu + (BASE) + 5), \
          W##t##6 = wload(wu + (BASE) + 6), W##t##7 = wload(wu + (BASE) + 7);

#define DOTU(u) { u32x4 hv = hp[u]; \
    a0 = dot_u4(W0##u, hv, a0); a1 = dot_u4(W1##u, hv, a1); \
    a2 = dot_u4(W2##u, hv, a2); a3 = dot_u4(W3##u, hv, a3); \
    a4 = dot_u4(W4##u, hv, a4); a5 = dot_u4(W5##u, hv, a5); }

__device__ __forceinline__ void rec_body(const uint32_t* __restrict__ whh,
        const float* __restrict__ bhh, const float* __restrict__ xg,
        f16* __restrict__ hout, float* __restrict__ state,
        int b, int C, char* smem) {
    uint32_t (*hq)[4][36] = (uint32_t(*)[4][36])smem; // padded quarters, broadcast-friendly

    int tid = threadIdx.x;
    int g = tid >> 2, q = tid & 3;

    const u32x4* wu = (const u32x4*)whh;
    // 6 rows x 8 u32x4 = 192 VGPRs of weights, defs are inline asm (unreloadable)
    LOADROW(0, (g)       * 32 + q * 8)
    LOADROW(1, (128 + g) * 32 + q * 8)
    LOADROW(2, (256 + g) * 32 + q * 8)
    LOADROW(3, (384 + g) * 32 + q * 8)
    LOADROW(4, (512 + g) * 32 + q * 8)
    LOADROW(5, (640 + g) * 32 + q * 8)
    // the asm loads are not compiler-tracked: drain them explicitly, then fence
    // the scheduler so no use is hoisted above the wait (guide rule #18)
    asm volatile("s_waitcnt vmcnt(0)" ::: "memory");
    __builtin_amdgcn_sched_barrier(0);

    int j = g + (q << 7); // valid for q<2
    float h_old = 0.0f, bhr = 0.0f, bhz = 0.0f, bhn = 0.0f;
    if (q < 2) {
        h_old = state[b * 256 + j];
        bhr = bhh[j]; bhz = bhh[256 + j]; bhn = bhh[512 + j];
        ((f16*)&hq[0][j >> 6][0])[j & 63] = (f16)h_old;
    }
    __syncthreads();

    const float* xgt = xg + (size_t)b * C * G_;
    f16* hob = hout + (size_t)b * C * H_;

    for (int tl = 0; tl < C; ++tl) {
        int p = tl & 1;
        float xr = 0, xz = 0, xn = 0;
        if (q < 2) { xr = xgt[j]; xz = xgt[256 + j]; xn = xgt[512 + j]; }

        const u32x4* hp = (const u32x4*)&hq[p][q][0];
        float a0 = 0, a1 = 0, a2 = 0, a3 = 0, a4 = 0, a5 = 0;
        DOTU(0) DOTU(1) DOTU(2) DOTU(3) DOTU(4) DOTU(5) DOTU(6) DOTU(7)

        a0 += __shfl_xor(a0, 1, 64); a0 += __shfl_xor(a0, 2, 64);
        a1 += __shfl_xor(a1, 1, 64); a1 += __shfl_xor(a1, 2, 64);
        a2 += __shfl_xor(a2, 1, 64); a2 += __shfl_xor(a2, 2, 64);
        a3 += __shfl_xor(a3, 1, 64); a3 += __shfl_xor(a3, 2, 64);
        a4 += __shfl_xor(a4, 1, 64); a4 += __shfl_xor(a4, 2, 64);
        a5 += __shfl_xor(a5, 1, 64); a5 += __shfl_xor(a5, 2, 64);

        if (q < 2) {
            float sumR = q ? a1 : a0;
            float sumZ = q ? a3 : a2;
            float sumN = q ? a5 : a4;
            float r = sigmoid_f(xr + sumR + bhr);
            float z = sigmoid_f(xz + sumZ + bhz);
            float n = tanh_f(xn + r * (sumN + bhn));
            h_old = z * (h_old - n) + n;   // (1-z)*n + z*h
            f16 hh = (f16)h_old;
            hob[(size_t)tl * H_ + j] = hh;
            ((f16*)&hq[p ^ 1][j >> 6][0])[j & 63] = hh;
        }
        __syncthreads();
        xgt += G_;
    }
    if (q < 2) state[b * 256 + j] = h_old;
}

// =======================================================================
// fused dispatch: blocks [0,64) rec0(i) | [64,128) rec1(i-1) |
//                 [128,128+C) xg0(i+1) | [128+C,128+2C) regressor(i-2)
// =======================================================================
__global__ __launch_bounds__(512, 2) void fused_step(int i, int nC, int C, int lgC,
        const float* __restrict__ x,
        const float* __restrict__ wih0, const float* __restrict__ bih0,
        const uint32_t* __restrict__ whh0, const float* __restrict__ bhh0,
        const uint32_t* __restrict__ whh1, const float* __restrict__ bhh1,
        const uint32_t* __restrict__ w1T, const float* __restrict__ b1,
        const float* __restrict__ w2, const float* __restrict__ b2,
        float* __restrict__ xg0a, float* __restrict__ xg0b,
        float* __restrict__ xg1b,
        f16* __restrict__ h1,
        f16* __restrict__ h2a, f16* __restrict__ h2b,
        float* __restrict__ st0, float* __restrict__ st1,
        float* __restrict__ out) {
    __shared__ __align__(16) char smem[33024];
    int blk = blockIdx.x;
    if (blk < 128) {
        const uint32_t* whh; const float* bhh; const float* xgp; f16* hout; float* st; int b;
        if (blk < 64) {
            if (i >= nC) return;
            whh = whh0; bhh = bhh0; xgp = (i & 1) ? xg0b : xg0a;
            hout = h1; st = st0; b = blk;
        } else {
            if (i < 1) return;
            whh = whh1; bhh = bhh1; xgp = xg1b;
            hout = ((i - 1) & 1) ? h2b : h2a; st = st1; b = blk - 64;
        }
        rec_body(whh, bhh, xgp, hout, st, b, C, smem);
    } else if (blk < 128 + C) {
        if (i + 1 >= nC) return;
        xg0_body(x, wih0, bih0, ((i + 1) & 1) ? xg0b : xg0a, (i + 1) * C, C, blk - 128, smem);
    } else {
        if (i < 2) return;
        reg_body((i & 1) ? h2b : h2a, w1T, b1, w2, b2, out, (i - 2) * C, C, lgC,
                 blk - 128 - C, smem);
    }
}

// ---------- standalone wrappers ----------
__global__ __launch_bounds__(512, 2) void xg0_stand(const float* __restrict__ x,
        const float* __restrict__ wih0, const float* __restrict__ bih0,
        float* __restrict__ xg, int t0, int C) {
    __shared__ __align__(16) char smem[4096];
    xg0_body(x, wih0, bih0, xg, t0, C, blockIdx.x, smem);
}

__global__ __launch_bounds__(512, 2) void reg_stand(const f16* __restrict__ h2,
        const uint32_t* __restrict__ w1T, const float* __restrict__ b1,
        const float* __restrict__ w2, const float* __restrict__ b2,
        float* __restrict__ out, int t0, int C, int lgC) {
    __shared__ __align__(16) char smem[33024];
    reg_body(h2, w1T, b1, w2, b2, out, t0, C, lgC, blockIdx.x, smem);
}

// ---------- xg1 = bih1 + h1 @ Wih1^T  (standalone, on critical path) ----------
__global__ __launch_bounds__(256) void xg1_kernel(const f16* __restrict__ h1,
        const uint32_t* __restrict__ wih1T, const float* __restrict__ bih1,
        float* __restrict__ xg, int C) {
    __shared__ u32x4 hs[64][32]; // 32 KB
    int tid = threadIdx.x;
    int m0 = blockIdx.x * 64;
    int gbase = blockIdx.y * 256;
    const u32x4* hsrc = (const u32x4*)h1 + (size_t)m0 * 32;
    #pragma unroll
    for (int it = 0; it < 8; ++it) {
        int o = tid + it * 256;
        hs[o >> 5][o & 31] = hsrc[o];
    }
    __syncthreads();
    int gg = tid & 31, mg = tid >> 5;
    const u32x4* wt = (const u32x4*)wih1T;
    float acc[8][8];
    #pragma unroll
    for (int i = 0; i < 8; ++i)
        #pragma unroll
        for (int r = 0; r < 8; ++r) acc[i][r] = 0.0f;
    for (int k8 = 0; k8 < 32; ++k8) {
        u32x4 w[8], h[8];
        #pragma unroll
        for (int i = 0; i < 8; ++i) w[i] = wt[(size_t)k8 * 768 + gbase + gg + 32 * i];
        #pragma unroll
        for (int r = 0; r < 8; ++r) h[r] = hs[mg * 8 + r][k8];
        #pragma unroll
        for (int i = 0; i < 8; ++i)
            #pragma unroll
            for (int r = 0; r < 8; ++r)
                acc[i][r] = dot_u4(w[i], h[r], acc[i][r]);
    }
    #pragma unroll
    for (int i = 0; i < 8; ++i) {
        int g = gbase + gg + 32 * i;
        float bias = bih1[g];
        #pragma unroll
        for (int r = 0; r < 8; ++r)
            xg[(size_t)(m0 + mg * 8 + r) * G_ + g] = acc[i][r] + bias;
    }
}

// ---------- host ----------
extern "C" void kernel_launch(void* const* d_in, const int* in_sizes, int n_in,
                              void* d_out, int out_size, void* d_ws, size_t ws_size,
                              hipStream_t stream) {
    const float* x    = (const float*)d_in[0];
    const float* Wih0 = (const float*)d_in[1];
    const float* Whh0 = (const float*)d_in[2];
    const float* bih0 = (const float*)d_in[3];
    const float* bhh0 = (const float*)d_in[4];
    const float* Wih1 = (const float*)d_in[5];
    const float* Whh1 = (const float*)d_in[6];
    const float* bih1 = (const float*)d_in[7];
    const float* bhh1 = (const float*)d_in[8];
    const float* W1   = (const float*)d_in[9];
    const float* b1   = (const float*)d_in[10];
    const float* W2   = (const float*)d_in[11];
    const float* b2   = (const float*)d_in[12];
    float* out = (float*)d_out;

    char* ws = (char*)d_ws;
    uint32_t* wcvt = (uint32_t*)ws;             // 327680 dwords
    const uint32_t* whh0_16 = wcvt;
    const uint32_t* whh1_16 = wcvt + 98304;
    const uint32_t* wih1T   = wcvt + 196608;
    const uint32_t* w1T     = wcvt + 294912;
    float* state0 = (float*)(ws + 1310720);
    float* state1 = (float*)(ws + 1310720 + 65536);
    size_t fixed = 1310720 + 2 * 65536;

    // per-chunk: xg0 x2 + xg1 (196608C each) + h1 (32768C) + h2 x2 (32768C each)
    int C = 512;
    while (C > 32 && fixed + (size_t)C * 688128 > ws_size) C >>= 1;
    int lgC = 0; while ((1 << lgC) < C) lgC++;
    int nC = T_ / C;

    char* p = ws + fixed;
    float* xg0_buf[2];
    xg0_buf[0] = (float*)p;  p += (size_t)C * 196608;
    xg0_buf[1] = (float*)p;  p += (size_t)C * 196608;
    float* xg1_buf = (float*)p; p += (size_t)C * 196608;
    f16* h1_buf = (f16*)p;   p += (size_t)C * 32768;
    f16* h2_buf[2];
    h2_buf[0] = (f16*)p;     p += (size_t)C * 32768;
    h2_buf[1] = (f16*)p;

    cvt_weights<<<1280, 256, 0, stream>>>(Whh0, Whh1, Wih1, W1, wcvt);
    hipMemsetAsync(state0, 0, 2 * 65536, stream);
    xg0_stand<<<C, 512, 0, stream>>>(x, Wih0, bih0, xg0_buf[0], 0, C);

    for (int i = 0; i <= nC; ++i) {
        fused_step<<<128 + 2 * C, 512, 0, stream>>>(i, nC, C, lgC,
            x, Wih0, bih0, whh0_16, bhh0, whh1_16, bhh1, w1T, b1, W2, b2,
            xg0_buf[0], xg0_buf[1], xg1_buf, h1_buf, h2_buf[0], h2_buf[1],
            state0, state1, out);
        if (i < nC)
            xg1_kernel<<<dim3(C, 3), 256, 0, stream>>>(h1_buf, wih1T, bih1, xg1_buf, C);
    }
    reg_stand<<<C, 512, 0, stream>>>(h2_buf[(nC - 1) & 1], w1T, b1, W2, b2, out,
                                     (nC - 1) * C, C, lgC);
}